// Round 13
// baseline (288.462 us; speedup 1.0000x reference)
//
#include <hip/hip_runtime.h>
#include <hip/hip_fp16.h>
#include <math.h>

#define N_NODES 100000
#define F_IN    100
#define HIDDEN  16
#define N_CLASS 18

#define BKT_SHIFT 7
#define BKT_NODES 128                                   // nodes per bucket
#define NBKT ((N_NODES + BKT_NODES - 1) / BKT_NODES)    // 782
#define TILE_B 4096                                     // edges per split tile
#define SORT_CAP 5120                                   // max edges per bucket

// ---- inline edge dtype detection: int64 little-endian (values < 2^31) has all-zero odd words
__device__ __forceinline__ int detect64(const int* __restrict__ ei) {
    int z = 1;
#pragma unroll
    for (int i = 0; i < 16; ++i)
        if (ei[2 * i + 1] != 0) z = 0;
    return z;
}

__device__ __forceinline__ int edge_at(const int* __restrict__ ei, long long idx, int is64) {
    return is64 ? ei[2 * idx] : ei[idx];
}

// ---- per-tile bucket histograms (2 tiles of 4096 per block) + global bucket counts
__global__ __launch_bounds__(512) void k_bcnt(const int* __restrict__ ei, long long E,
                                              int nt,
                                              int* __restrict__ bcnt,
                                              int* __restrict__ thist) {
    __shared__ int hist0[NBKT];
    __shared__ int hist1[NBKT];
    int tid = threadIdx.x;
    for (int i = tid; i < NBKT; i += 512) { hist0[i] = 0; hist1[i] = 0; }
    __syncthreads();
    int is64 = detect64(ei);
    long long base = (long long)blockIdx.x * (2 * TILE_B);
    long long rem = E - base;
    int ntot = (int)((rem < (long long)(2 * TILE_B)) ? rem : (long long)(2 * TILE_B));
    int n0 = ntot < TILE_B ? ntot : TILE_B;
    int n1 = ntot - n0;
    for (int i = tid; i < n0; i += 512) {
        int d = edge_at(ei, E + base + i, is64);
        atomicAdd(&hist0[d >> BKT_SHIFT], 1);
    }
    for (int i = tid; i < n1; i += 512) {
        int d = edge_at(ei, E + base + TILE_B + i, is64);
        atomicAdd(&hist1[d >> BKT_SHIFT], 1);
    }
    __syncthreads();
    int t0 = blockIdx.x * 2, t1 = t0 + 1;
    for (int b = tid; b < NBKT; b += 512) {
        int c0 = hist0[b], c1 = hist1[b];
        thist[t0 * NBKT + b] = c0;
        if (n1 > 0) thist[t1 * NBKT + b] = c1;
        int c = c0 + c1;
        if (c) atomicAdd(&bcnt[b], c);
    }
}

// ---- per-bucket prefix over tiles (block b), with bkt_base reduction fused in
__global__ __launch_bounds__(256) void k_tscan(const int* __restrict__ thist,
                                               const int* __restrict__ bcnt,
                                               int nt,
                                               int* __restrict__ tbase,
                                               int* __restrict__ bkt_base) {
    __shared__ int ts[256];
    __shared__ int red[256];
    int b = blockIdx.x, tid = threadIdx.x;
    // bkt_base[b] = sum of bcnt[0..b-1]
    int partial = 0;
    for (int i = tid; i < b; i += 256) partial += bcnt[i];
    red[tid] = partial;
    __syncthreads();
    for (int off = 128; off > 0; off >>= 1) {
        if (tid < off) red[tid] += red[tid + off];
        __syncthreads();
    }
    int base = red[0];
    if (tid == 0) bkt_base[b] = base;
    // prefix over tiles for this bucket
    int t0 = tid * 4;
    int c[4];
#pragma unroll
    for (int j = 0; j < 4; ++j) {
        int t = t0 + j;
        c[j] = (t < nt) ? thist[t * NBKT + b] : 0;
    }
    int s = c[0] + c[1] + c[2] + c[3];
    ts[tid] = s;
    __syncthreads();
    for (int off = 1; off < 256; off <<= 1) {
        int t = (tid >= off) ? ts[tid - off] : 0;
        __syncthreads();
        ts[tid] += t;
        __syncthreads();
    }
    int run = base + ts[tid] - s;
#pragma unroll
    for (int j = 0; j < 4; ++j) {
        int t = t0 + j;
        if (t < nt) { tbase[t * NBKT + b] = run; run += c[j]; }
    }
}

// ---- split: per-tile counting sort by bucket, deterministic positions (no atomics)
// pairs[pos] = src | (dst&127)<<17
__global__ __launch_bounds__(512) void k_bucket(const int* __restrict__ ei, long long E,
                                                const int* __restrict__ thist,
                                                const int* __restrict__ tbase,
                                                int* __restrict__ pairs) {
    __shared__ int lbase[NBKT];
    __shared__ int gbase[NBKT];
    __shared__ int lcur[NBKT];
    __shared__ unsigned short perm[TILE_B];
    __shared__ int ts[512];
    int tid = threadIdx.x;
    int t = blockIdx.x;
    int is64 = detect64(ei);
    long long e0 = (long long)t * TILE_B;
    int n = (int)(((E - e0) < (long long)TILE_B) ? (E - e0) : (long long)TILE_B);

    int b0 = tid * 2;
    int h0 = (b0 + 0 < NBKT) ? thist[t * NBKT + b0 + 0] : 0;
    int h1 = (b0 + 1 < NBKT) ? thist[t * NBKT + b0 + 1] : 0;
    int tsum = h0 + h1;
    ts[tid] = tsum;
    for (int b = tid; b < NBKT; b += 512) gbase[b] = tbase[t * NBKT + b];
    __syncthreads();
    for (int off = 1; off < 512; off <<= 1) {
        int tv = (tid >= off) ? ts[tid - off] : 0;
        __syncthreads();
        ts[tid] += tv;
        __syncthreads();
    }
    int eb = ts[tid] - tsum;
    if (b0 + 0 < NBKT) { lbase[b0 + 0] = eb;      lcur[b0 + 0] = eb; }
    if (b0 + 1 < NBKT) { lbase[b0 + 1] = eb + h0; lcur[b0 + 1] = eb + h0; }
    __syncthreads();

    for (int i = tid; i < n; i += 512) {
        int d = edge_at(ei, E + e0 + i, is64);
        int l = atomicAdd(&lcur[d >> BKT_SHIFT], 1);
        perm[l] = (unsigned short)i;
    }
    __syncthreads();

    for (int k = tid; k < n; k += 512) {
        int i = perm[k];
        int s = edge_at(ei, e0 + i, is64);
        int d = edge_at(ei, E + e0 + i, is64);
        int b = d >> BKT_SHIFT;
        int pos = gbase[b] + (k - lbase[b]);
        pairs[pos] = s | ((d & (BKT_NODES - 1)) << 17);
    }
}

// ---- fused CSR finalize: per bucket -> per-node counts, dinv, row_start, in-place sort
__global__ __launch_bounds__(256) void k_csr(const int* __restrict__ bkt_base,
                                             int* __restrict__ pairs,
                                             int* __restrict__ row_start,
                                             float* __restrict__ dinv,
                                             int Ei) {
    __shared__ int stage[SORT_CAP];
    __shared__ int lc[BKT_NODES];
    __shared__ int rs[BKT_NODES];
    int bk = blockIdx.x, tid = threadIdx.x;
    int i0 = bkt_base[bk];
    int i1 = (bk == NBKT - 1) ? Ei : bkt_base[bk + 1];
    int m = i1 - i0;
    if (tid < BKT_NODES) lc[tid] = 0;
    __syncthreads();
    for (int i = tid; i < m; i += 256) {
        int v = pairs[i0 + i];
        stage[i] = v;
        atomicAdd(&lc[v >> 17], 1);
    }
    __syncthreads();
    if (tid < BKT_NODES) rs[tid] = lc[tid];
    __syncthreads();
    for (int off = 1; off < BKT_NODES; off <<= 1) {
        int t = (tid >= off && tid < BKT_NODES) ? rs[tid - off] : 0;
        __syncthreads();
        if (tid < BKT_NODES) rs[tid] += t;
        __syncthreads();
    }
    int node = bk * BKT_NODES + tid;
    int ex = 0;
    if (tid < BKT_NODES) {
        int c = lc[tid];
        ex = rs[tid] - c;
        if (node < N_NODES) {
            row_start[node] = i0 + ex;
            dinv[node] = rsqrtf((float)c + 1.0f);
        }
    }
    if (bk == NBKT - 1 && tid == 0) row_start[N_NODES] = i1;
    __syncthreads();
    if (tid < BKT_NODES) lc[tid] = ex;
    __syncthreads();
    for (int i = tid; i < m; i += 256) {
        int v = stage[i];
        int pos = atomicAdd(&lc[v >> 17], 1);
        pairs[i0 + pos] = v & 0x1FFFF;
    }
}

// ---- tmpp1 = fp16( dinv * relu(x@W1+b1) )  — NO conv transform (moved to aggr epilogue)
__global__ __launch_bounds__(512) void k_lin1h(const float* __restrict__ x,
                                               const float* __restrict__ W1,
                                               const float* __restrict__ b1,
                                               const float* __restrict__ dinv,
                                               __half* __restrict__ tmpp1) {
    __shared__ float sW[F_IN * HIDDEN];
    __shared__ float sb[HIDDEN];
    for (int i = threadIdx.x; i < F_IN * HIDDEN; i += 512) sW[i] = W1[i];
    if (threadIdx.x < HIDDEN) sb[threadIdx.x] = b1[threadIdx.x];
    __syncthreads();
    int node = blockIdx.x * 256 + (threadIdx.x >> 1);
    int half = threadIdx.x & 1;
    if (node >= N_NODES) return;

    float acc[HIDDEN];
#pragma unroll
    for (int j = 0; j < HIDDEN; ++j) acc[j] = half ? 0.0f : sb[j];

    const float4* x4 = reinterpret_cast<const float4*>(x + (long long)node * F_IN);
    int k40 = half ? 13 : 0;
    int k41 = half ? 25 : 13;
    for (int k4 = k40; k4 < k41; ++k4) {
        float4 xv = x4[k4];
        const float* w = &sW[k4 * 4 * HIDDEN];
#pragma unroll
        for (int j = 0; j < HIDDEN; ++j) {
            acc[j] += xv.x * w[0 * HIDDEN + j];
            acc[j] += xv.y * w[1 * HIDDEN + j];
            acc[j] += xv.z * w[2 * HIDDEN + j];
            acc[j] += xv.w * w[3 * HIDDEN + j];
        }
    }
#pragma unroll
    for (int j = 0; j < HIDDEN; ++j) {
        acc[j] += __shfl_xor(acc[j], 1);
        acc[j] = fmaxf(acc[j], 0.0f);
    }
    // select this half's 8 features with static indices
    float w8[8];
#pragma unroll
    for (int j = 0; j < 8; ++j) w8[j] = half ? acc[8 + j] : acc[j];
    float di = dinv[node];
    __half2 p[4];
#pragma unroll
    for (int t = 0; t < 4; ++t)
        p[t] = __floats2half2_rn(di * w8[2 * t], di * w8[2 * t + 1]);
    *reinterpret_cast<float4*>(tmpp1 + (long long)node * HIDDEN + half * 8) =
        *reinterpret_cast<const float4*>(p);
}

#define WSHFL4(dst, src, m)                    \
    dst.x = __shfl_xor(src.x, m);              \
    dst.y = __shfl_xor(src.y, m);              \
    dst.z = __shfl_xor(src.z, m);              \
    dst.w = __shfl_xor(src.w, m);

// ---- conv1 aggregation + fused 16x16 transform epilogue
// tmpp2[n] = fp16( dinv_n * relu( dinv_n * ((acc+self) @ Wc0) + bc0 ) )
__global__ __launch_bounds__(256) void k_aggr_t(const int* __restrict__ row_start,
                                                const int* __restrict__ srcs,
                                                const __half* __restrict__ tmpp1,
                                                const float* __restrict__ dinv,
                                                const float* __restrict__ Wc0,
                                                const float* __restrict__ bc0,
                                                __half* __restrict__ tmpp2) {
    __shared__ __align__(16) float sWt[HIDDEN * HIDDEN];   // transposed: sWt[j*16+k]
    __shared__ float sb[HIDDEN];
    {
        int t = threadIdx.x;               // t = k*16+j
        int k = t >> 4, j = t & 15;
        sWt[j * 16 + k] = Wc0[t];
        if (t < HIDDEN) sb[t] = bc0[t];
    }
    __syncthreads();
    int wave = (blockIdx.x * 256 + threadIdx.x) >> 6;
    if (wave >= N_NODES) return;
    int lane = threadIdx.x & 63;
    int es = lane >> 2;
    int fq = lane & 3;
    int j0 = fq * 4;

    int s0 = row_start[wave], s1 = row_start[wave + 1];
    float a0 = 0.0f, a1 = 0.0f, a2 = 0.0f, a3 = 0.0f;
    for (int e = s0 + es; e < s1; e += 16) {
        int src = srcs[e];
        float2 rv = *(reinterpret_cast<const float2*>(
                          tmpp1 + (long long)src * HIDDEN) + fq);
        const __half2* h2 = reinterpret_cast<const __half2*>(&rv);
        float2 f0 = __half22float2(h2[0]);
        float2 f1 = __half22float2(h2[1]);
        a0 += f0.x; a1 += f0.y; a2 += f1.x; a3 += f1.y;
    }
#pragma unroll
    for (int m = 4; m <= 32; m <<= 1) {
        a0 += __shfl_xor(a0, m);
        a1 += __shfl_xor(a1, m);
        a2 += __shfl_xor(a2, m);
        a3 += __shfl_xor(a3, m);
    }
    // self term (all lanes)
    float2 sv = *(reinterpret_cast<const float2*>(
                      tmpp1 + (long long)wave * HIDDEN) + fq);
    const __half2* s2 = reinterpret_cast<const __half2*>(&sv);
    float2 f0 = __half22float2(s2[0]);
    float2 f1 = __half22float2(s2[1]);
    float4 t0;  // this lane's 4 features of the aggregate (global idx j0..j0+3)
    t0.x = a0 + f0.x; t0.y = a1 + f0.y; t0.z = a2 + f1.x; t0.w = a3 + f1.y;
    // all-gather across fq: block b holds features of (fq^b)
    float4 t1, t2, t3;
    WSHFL4(t1, t0, 1)
    WSHFL4(t2, t0, 2)
    WSHFL4(t3, t1, 2)
    float di = dinv[wave];
    // out[j] for j = j0..j0+3 ; weights read transposed as float4
    float o[4];
#pragma unroll
    for (int j = 0; j < 4; ++j) {
        const float* wr = &sWt[(j0 + j) * 16];
        float4 w0 = *reinterpret_cast<const float4*>(wr + (fq ^ 0) * 4);
        float4 w1 = *reinterpret_cast<const float4*>(wr + (fq ^ 1) * 4);
        float4 w2 = *reinterpret_cast<const float4*>(wr + (fq ^ 2) * 4);
        float4 w3 = *reinterpret_cast<const float4*>(wr + (fq ^ 3) * 4);
        float acc = t0.x * w0.x + t0.y * w0.y + t0.z * w0.z + t0.w * w0.w
                  + t1.x * w1.x + t1.y * w1.y + t1.z * w1.z + t1.w * w1.w
                  + t2.x * w2.x + t2.y * w2.y + t2.z * w2.z + t2.w * w2.w
                  + t3.x * w3.x + t3.y * w3.y + t3.z * w3.z + t3.w * w3.w;
        o[j] = fmaxf(di * acc + sb[j0 + j], 0.0f);
    }
    if (es == 0) {
        __half2 p[2];
        p[0] = __floats2half2_rn(di * o[0], di * o[1]);
        p[1] = __floats2half2_rn(di * o[2], di * o[3]);
        *reinterpret_cast<float2*>(tmpp2 + (long long)wave * HIDDEN + j0) =
            *reinterpret_cast<const float2*>(p);
    }
}

// ---- conv2 aggregation + fused 16x16 transform + 16x18 classifier + log_softmax
__global__ __launch_bounds__(256) void k_aggr_o(const int* __restrict__ row_start,
                                                const int* __restrict__ srcs,
                                                const __half* __restrict__ tmpp2,
                                                const float* __restrict__ dinv,
                                                const float* __restrict__ Wc1,
                                                const float* __restrict__ bc1,
                                                const float* __restrict__ W2,
                                                const float* __restrict__ b2,
                                                float* __restrict__ out) {
    __shared__ __align__(16) float sWt[HIDDEN * HIDDEN];    // Wc1 transposed j*16+k
    __shared__ float sb1[HIDDEN];
    __shared__ __align__(16) float sW2t[N_CLASS * HIDDEN];  // W2 transposed c*16+k
    __shared__ float sb2[N_CLASS];
    {
        int t = threadIdx.x;
        int k = t >> 4, j = t & 15;
        sWt[j * 16 + k] = Wc1[t];
        if (t < HIDDEN) sb1[t] = bc1[t];
        if (t < N_CLASS) sb2[t] = b2[t];
    }
    for (int t = threadIdx.x; t < HIDDEN * N_CLASS; t += 256) {
        int k = t / N_CLASS, c = t % N_CLASS;
        sW2t[c * 16 + k] = W2[t];
    }
    __syncthreads();
    int wave = (blockIdx.x * 256 + threadIdx.x) >> 6;
    if (wave >= N_NODES) return;
    int lane = threadIdx.x & 63;
    int es = lane >> 2;
    int fq = lane & 3;
    int j0 = fq * 4;

    int s0 = row_start[wave], s1 = row_start[wave + 1];
    float a0 = 0.0f, a1 = 0.0f, a2 = 0.0f, a3 = 0.0f;
    for (int e = s0 + es; e < s1; e += 16) {
        int src = srcs[e];
        float2 rv = *(reinterpret_cast<const float2*>(
                          tmpp2 + (long long)src * HIDDEN) + fq);
        const __half2* h2 = reinterpret_cast<const __half2*>(&rv);
        float2 f0 = __half22float2(h2[0]);
        float2 f1 = __half22float2(h2[1]);
        a0 += f0.x; a1 += f0.y; a2 += f1.x; a3 += f1.y;
    }
#pragma unroll
    for (int m = 4; m <= 32; m <<= 1) {
        a0 += __shfl_xor(a0, m);
        a1 += __shfl_xor(a1, m);
        a2 += __shfl_xor(a2, m);
        a3 += __shfl_xor(a3, m);
    }
    float2 sv = *(reinterpret_cast<const float2*>(
                      tmpp2 + (long long)wave * HIDDEN) + fq);
    const __half2* s2 = reinterpret_cast<const __half2*>(&sv);
    float2 f0 = __half22float2(s2[0]);
    float2 f1 = __half22float2(s2[1]);
    float4 t0;
    t0.x = a0 + f0.x; t0.y = a1 + f0.y; t0.z = a2 + f1.x; t0.w = a3 + f1.y;
    float4 t1, t2, t3;
    WSHFL4(t1, t0, 1)
    WSHFL4(t2, t0, 2)
    WSHFL4(t3, t1, 2)
    float di = dinv[wave];
    // h2[j0..j0+3] = relu(di*(t@Wc1)+bc1)
    float4 hq;
    {
        float o[4];
#pragma unroll
        for (int j = 0; j < 4; ++j) {
            const float* wr = &sWt[(j0 + j) * 16];
            float4 w0 = *reinterpret_cast<const float4*>(wr + (fq ^ 0) * 4);
            float4 w1 = *reinterpret_cast<const float4*>(wr + (fq ^ 1) * 4);
            float4 w2 = *reinterpret_cast<const float4*>(wr + (fq ^ 2) * 4);
            float4 w3 = *reinterpret_cast<const float4*>(wr + (fq ^ 3) * 4);
            float acc = t0.x * w0.x + t0.y * w0.y + t0.z * w0.z + t0.w * w0.w
                      + t1.x * w1.x + t1.y * w1.y + t1.z * w1.z + t1.w * w1.w
                      + t2.x * w2.x + t2.y * w2.y + t2.z * w2.z + t2.w * w2.w
                      + t3.x * w3.x + t3.y * w3.y + t3.z * w3.z + t3.w * w3.w;
            o[j] = fmaxf(di * acc + sb1[j0 + j], 0.0f);
        }
        hq.x = o[0]; hq.y = o[1]; hq.z = o[2]; hq.w = o[3];
    }
    // all-gather h2 across fq
    float4 c0 = hq, c1, c2, c3;
    WSHFL4(c1, c0, 1)
    WSHFL4(c2, c0, 2)
    WSHFL4(c3, c1, 2)
    // class partition: fq0 -> 0..4, fq1 -> 5..9, fq2 -> 10..13, fq3 -> 14..17
    int cs = (fq < 2) ? fq * 5 : 10 + (fq - 2) * 4;
    int nc = (fq < 2) ? 5 : 4;
    float z[5];
#pragma unroll
    for (int ci = 0; ci < 5; ++ci) {
        int c = cs + ci;
        int cc = c > 17 ? 17 : c;
        const float* wr = &sW2t[cc * 16];
        float4 w0 = *reinterpret_cast<const float4*>(wr + (fq ^ 0) * 4);
        float4 w1 = *reinterpret_cast<const float4*>(wr + (fq ^ 1) * 4);
        float4 w2 = *reinterpret_cast<const float4*>(wr + (fq ^ 2) * 4);
        float4 w3 = *reinterpret_cast<const float4*>(wr + (fq ^ 3) * 4);
        float acc = c0.x * w0.x + c0.y * w0.y + c0.z * w0.z + c0.w * w0.w
                  + c1.x * w1.x + c1.y * w1.y + c1.z * w1.z + c1.w * w1.w
                  + c2.x * w2.x + c2.y * w2.y + c2.z * w2.z + c2.w * w2.w
                  + c3.x * w3.x + c3.y * w3.y + c3.z * w3.z + c3.w * w3.w;
        z[ci] = (ci < nc) ? (sb2[cc] + acc) : -1e30f;
    }
    // log-sum-exp across all 18 classes (4 fq lanes hold disjoint subsets)
    float m = z[0];
#pragma unroll
    for (int ci = 1; ci < 5; ++ci) m = fmaxf(m, z[ci]);
    m = fmaxf(m, __shfl_xor(m, 1));
    m = fmaxf(m, __shfl_xor(m, 2));
    float s = 0.0f;
#pragma unroll
    for (int ci = 0; ci < 5; ++ci) s += expf(z[ci] - m);
    s += __shfl_xor(s, 1);
    s += __shfl_xor(s, 2);
    float l = m + logf(s);
    if (es == 0) {
        float* orow = out + (long long)wave * N_CLASS + cs;
#pragma unroll
        for (int ci = 0; ci < 5; ++ci)
            if (ci < nc) orow[ci] = z[ci] - l;
    }
}

static inline char* align256(char* p) {
    return (char*)(((size_t)p + 255) & ~(size_t)255);
}

extern "C" void kernel_launch(void* const* d_in, const int* in_sizes, int n_in,
                              void* d_out, int out_size, void* d_ws, size_t ws_size,
                              hipStream_t stream) {
    const float* x   = (const float*)d_in[0];
    const int*   ei  = (const int*)d_in[1];
    const float* W1  = (const float*)d_in[2];
    const float* b1  = (const float*)d_in[3];
    const float* Wc0 = (const float*)d_in[4];
    const float* bc0 = (const float*)d_in[5];
    const float* Wc1 = (const float*)d_in[6];
    const float* bc1 = (const float*)d_in[7];
    const float* W2  = (const float*)d_in[8];
    const float* b2  = (const float*)d_in[9];
    float* out = (float*)d_out;

    long long E = (long long)in_sizes[1] / 2;
    int nt = (int)((E + TILE_B - 1) / TILE_B);

    char* p = (char*)d_ws;
    float* dinv    = (float*)p;          p = align256(p + sizeof(float) * N_NODES);
    int* row_start = (int*)p;            p = align256(p + sizeof(int) * (N_NODES + 1));
    int* bcnt      = (int*)p;            p = align256(p + sizeof(int) * NBKT);
    int* bkt_base  = (int*)p;            p = align256(p + sizeof(int) * (NBKT + 1));
    int* thist     = (int*)p;            p = align256(p + sizeof(int) * (size_t)nt * NBKT);
    int* tbase     = (int*)p;            p = align256(p + sizeof(int) * (size_t)nt * NBKT);
    int* pairs     = (int*)p;            p = align256(p + sizeof(int) * E);
    __half* tmpp1  = (__half*)p;         p = align256(p + sizeof(__half) * (size_t)N_NODES * HIDDEN);
    __half* tmpp2  = (__half*)p;         p = align256(p + sizeof(__half) * (size_t)N_NODES * HIDDEN);

    const int nblk_node = (N_NODES + 255) / 256;
    const int nblk_bcnt = (int)((E + 2 * TILE_B - 1) / (2 * TILE_B));
    const int nblk_aggr = (int)(((long long)N_NODES * 64 + 255) / 256);

    hipMemsetAsync(bcnt, 0, sizeof(int) * NBKT, stream);

    k_bcnt<<<nblk_bcnt, 512, 0, stream>>>(ei, E, nt, bcnt, thist);
    k_tscan<<<NBKT, 256, 0, stream>>>(thist, bcnt, nt, tbase, bkt_base);
    k_bucket<<<nt, 512, 0, stream>>>(ei, E, thist, tbase, pairs);
    k_csr<<<NBKT, 256, 0, stream>>>(bkt_base, pairs, row_start, dinv, (int)E);

    k_lin1h<<<nblk_node, 512, 0, stream>>>(x, W1, b1, dinv, tmpp1);

    k_aggr_t<<<nblk_aggr, 256, 0, stream>>>(row_start, pairs, tmpp1, dinv, Wc0, bc0, tmpp2);
    k_aggr_o<<<nblk_aggr, 256, 0, stream>>>(row_start, pairs, tmpp2, dinv, Wc1, bc1, W2, b2, out);
}

// Round 14
// 226.310 us; speedup vs baseline: 1.2746x; 1.2746x over previous
//
#include <hip/hip_runtime.h>
#include <hip/hip_fp16.h>
#include <math.h>

#define N_NODES 100000
#define F_IN    100
#define HIDDEN  16
#define N_CLASS 18

#define BKT_SHIFT 7
#define BKT_NODES 128                                   // nodes per bucket
#define NBKT ((N_NODES + BKT_NODES - 1) / BKT_NODES)    // 782
#define TILE_B 4096                                     // edges per split tile
#define SORT_CAP 5120                                   // max edges per bucket

// ---- inline edge dtype detection: int64 little-endian (values < 2^31) has all-zero odd words
__device__ __forceinline__ int detect64(const int* __restrict__ ei) {
    int z = 1;
#pragma unroll
    for (int i = 0; i < 16; ++i)
        if (ei[2 * i + 1] != 0) z = 0;
    return z;
}

__device__ __forceinline__ int edge_at(const int* __restrict__ ei, long long idx, int is64) {
    return is64 ? ei[2 * idx] : ei[idx];
}

// ---- per-tile bucket histograms (2 tiles of 4096 per block) + global bucket counts
__global__ __launch_bounds__(512) void k_bcnt(const int* __restrict__ ei, long long E,
                                              int nt,
                                              int* __restrict__ bcnt,
                                              int* __restrict__ thist) {
    __shared__ int hist0[NBKT];
    __shared__ int hist1[NBKT];
    int tid = threadIdx.x;
    for (int i = tid; i < NBKT; i += 512) { hist0[i] = 0; hist1[i] = 0; }
    __syncthreads();
    int is64 = detect64(ei);
    long long base = (long long)blockIdx.x * (2 * TILE_B);
    long long rem = E - base;
    int ntot = (int)((rem < (long long)(2 * TILE_B)) ? rem : (long long)(2 * TILE_B));
    int n0 = ntot < TILE_B ? ntot : TILE_B;
    int n1 = ntot - n0;
    for (int i = tid; i < n0; i += 512) {
        int d = edge_at(ei, E + base + i, is64);
        atomicAdd(&hist0[d >> BKT_SHIFT], 1);
    }
    for (int i = tid; i < n1; i += 512) {
        int d = edge_at(ei, E + base + TILE_B + i, is64);
        atomicAdd(&hist1[d >> BKT_SHIFT], 1);
    }
    __syncthreads();
    int t0 = blockIdx.x * 2, t1 = t0 + 1;
    for (int b = tid; b < NBKT; b += 512) {
        int c0 = hist0[b], c1 = hist1[b];
        thist[t0 * NBKT + b] = c0;
        if (n1 > 0) thist[t1 * NBKT + b] = c1;
        int c = c0 + c1;
        if (c) atomicAdd(&bcnt[b], c);
    }
}

// ---- per-bucket prefix over tiles (block b), with bkt_base reduction fused in
__global__ __launch_bounds__(256) void k_tscan(const int* __restrict__ thist,
                                               const int* __restrict__ bcnt,
                                               int nt,
                                               int* __restrict__ tbase,
                                               int* __restrict__ bkt_base) {
    __shared__ int ts[256];
    __shared__ int red[256];
    int b = blockIdx.x, tid = threadIdx.x;
    int partial = 0;
    for (int i = tid; i < b; i += 256) partial += bcnt[i];
    red[tid] = partial;
    __syncthreads();
    for (int off = 128; off > 0; off >>= 1) {
        if (tid < off) red[tid] += red[tid + off];
        __syncthreads();
    }
    int base = red[0];
    if (tid == 0) bkt_base[b] = base;
    int t0 = tid * 4;
    int c[4];
#pragma unroll
    for (int j = 0; j < 4; ++j) {
        int t = t0 + j;
        c[j] = (t < nt) ? thist[t * NBKT + b] : 0;
    }
    int s = c[0] + c[1] + c[2] + c[3];
    ts[tid] = s;
    __syncthreads();
    for (int off = 1; off < 256; off <<= 1) {
        int t = (tid >= off) ? ts[tid - off] : 0;
        __syncthreads();
        ts[tid] += t;
        __syncthreads();
    }
    int run = base + ts[tid] - s;
#pragma unroll
    for (int j = 0; j < 4; ++j) {
        int t = t0 + j;
        if (t < nt) { tbase[t * NBKT + b] = run; run += c[j]; }
    }
}

// ---- split: per-tile counting sort by bucket, deterministic positions (no atomics)
__global__ __launch_bounds__(512) void k_bucket(const int* __restrict__ ei, long long E,
                                                const int* __restrict__ thist,
                                                const int* __restrict__ tbase,
                                                int* __restrict__ pairs) {
    __shared__ int lbase[NBKT];
    __shared__ int gbase[NBKT];
    __shared__ int lcur[NBKT];
    __shared__ unsigned short perm[TILE_B];
    __shared__ int ts[512];
    int tid = threadIdx.x;
    int t = blockIdx.x;
    int is64 = detect64(ei);
    long long e0 = (long long)t * TILE_B;
    int n = (int)(((E - e0) < (long long)TILE_B) ? (E - e0) : (long long)TILE_B);

    int b0 = tid * 2;
    int h0 = (b0 + 0 < NBKT) ? thist[t * NBKT + b0 + 0] : 0;
    int h1 = (b0 + 1 < NBKT) ? thist[t * NBKT + b0 + 1] : 0;
    int tsum = h0 + h1;
    ts[tid] = tsum;
    for (int b = tid; b < NBKT; b += 512) gbase[b] = tbase[t * NBKT + b];
    __syncthreads();
    for (int off = 1; off < 512; off <<= 1) {
        int tv = (tid >= off) ? ts[tid - off] : 0;
        __syncthreads();
        ts[tid] += tv;
        __syncthreads();
    }
    int eb = ts[tid] - tsum;
    if (b0 + 0 < NBKT) { lbase[b0 + 0] = eb;      lcur[b0 + 0] = eb; }
    if (b0 + 1 < NBKT) { lbase[b0 + 1] = eb + h0; lcur[b0 + 1] = eb + h0; }
    __syncthreads();

    for (int i = tid; i < n; i += 512) {
        int d = edge_at(ei, E + e0 + i, is64);
        int l = atomicAdd(&lcur[d >> BKT_SHIFT], 1);
        perm[l] = (unsigned short)i;
    }
    __syncthreads();

    for (int k = tid; k < n; k += 512) {
        int i = perm[k];
        int s = edge_at(ei, e0 + i, is64);
        int d = edge_at(ei, E + e0 + i, is64);
        int b = d >> BKT_SHIFT;
        int pos = gbase[b] + (k - lbase[b]);
        pairs[pos] = s | ((d & (BKT_NODES - 1)) << 17);
    }
}

// ---- fused CSR finalize: per bucket -> per-node counts, dinv, row_start, in-place sort
__global__ __launch_bounds__(256) void k_csr(const int* __restrict__ bkt_base,
                                             int* __restrict__ pairs,
                                             int* __restrict__ row_start,
                                             float* __restrict__ dinv,
                                             int Ei) {
    __shared__ int stage[SORT_CAP];
    __shared__ int lc[BKT_NODES];
    __shared__ int rs[BKT_NODES];
    int bk = blockIdx.x, tid = threadIdx.x;
    int i0 = bkt_base[bk];
    int i1 = (bk == NBKT - 1) ? Ei : bkt_base[bk + 1];
    int m = i1 - i0;
    if (tid < BKT_NODES) lc[tid] = 0;
    __syncthreads();
    for (int i = tid; i < m; i += 256) {
        int v = pairs[i0 + i];
        stage[i] = v;
        atomicAdd(&lc[v >> 17], 1);
    }
    __syncthreads();
    if (tid < BKT_NODES) rs[tid] = lc[tid];
    __syncthreads();
    for (int off = 1; off < BKT_NODES; off <<= 1) {
        int t = (tid >= off && tid < BKT_NODES) ? rs[tid - off] : 0;
        __syncthreads();
        if (tid < BKT_NODES) rs[tid] += t;
        __syncthreads();
    }
    int node = bk * BKT_NODES + tid;
    int ex = 0;
    if (tid < BKT_NODES) {
        int c = lc[tid];
        ex = rs[tid] - c;
        if (node < N_NODES) {
            row_start[node] = i0 + ex;
            dinv[node] = rsqrtf((float)c + 1.0f);
        }
    }
    if (bk == NBKT - 1 && tid == 0) row_start[N_NODES] = i1;
    __syncthreads();
    if (tid < BKT_NODES) lc[tid] = ex;
    __syncthreads();
    for (int i = tid; i < m; i += 256) {
        int v = stage[i];
        int pos = atomicAdd(&lc[v >> 17], 1);
        pairs[i0 + pos] = v & 0x1FFFF;
    }
}

// ---- tmpp1 = fp16( dinv * relu(x@W1+b1) )
__global__ __launch_bounds__(512) void k_lin1h(const float* __restrict__ x,
                                               const float* __restrict__ W1,
                                               const float* __restrict__ b1,
                                               const float* __restrict__ dinv,
                                               __half* __restrict__ tmpp1) {
    __shared__ float sW[F_IN * HIDDEN];
    __shared__ float sb[HIDDEN];
    for (int i = threadIdx.x; i < F_IN * HIDDEN; i += 512) sW[i] = W1[i];
    if (threadIdx.x < HIDDEN) sb[threadIdx.x] = b1[threadIdx.x];
    __syncthreads();
    int node = blockIdx.x * 256 + (threadIdx.x >> 1);
    int half = threadIdx.x & 1;
    if (node >= N_NODES) return;

    float acc[HIDDEN];
#pragma unroll
    for (int j = 0; j < HIDDEN; ++j) acc[j] = half ? 0.0f : sb[j];

    const float4* x4 = reinterpret_cast<const float4*>(x + (long long)node * F_IN);
    int k40 = half ? 13 : 0;
    int k41 = half ? 25 : 13;
    for (int k4 = k40; k4 < k41; ++k4) {
        float4 xv = x4[k4];
        const float* w = &sW[k4 * 4 * HIDDEN];
#pragma unroll
        for (int j = 0; j < HIDDEN; ++j) {
            acc[j] += xv.x * w[0 * HIDDEN + j];
            acc[j] += xv.y * w[1 * HIDDEN + j];
            acc[j] += xv.z * w[2 * HIDDEN + j];
            acc[j] += xv.w * w[3 * HIDDEN + j];
        }
    }
#pragma unroll
    for (int j = 0; j < HIDDEN; ++j) {
        acc[j] += __shfl_xor(acc[j], 1);
        acc[j] = fmaxf(acc[j], 0.0f);
    }
    float w8[8];
#pragma unroll
    for (int j = 0; j < 8; ++j) w8[j] = half ? acc[8 + j] : acc[j];
    float di = dinv[node];
    __half2 p[4];
#pragma unroll
    for (int t = 0; t < 4; ++t)
        p[t] = __floats2half2_rn(di * w8[2 * t], di * w8[2 * t + 1]);
    *reinterpret_cast<float4*>(tmpp1 + (long long)node * HIDDEN + half * 8) =
        *reinterpret_cast<const float4*>(p);
}

// ---- conv1 aggregation + register-weight transform epilogue (ZERO LDS)
// tmpp2[n] = fp16( dinv_n * relu( dinv_n * ((agg+self) @ Wc0) + bc0 ) )
// lane (es=lane>>2, fq=lane&3): gather 8B quarters; lane holds W[es][fq*4..+3] in 1 float4
__global__ __launch_bounds__(256) void k_aggr_t(const int* __restrict__ row_start,
                                                const int* __restrict__ srcs,
                                                const __half* __restrict__ tmpp1,
                                                const float* __restrict__ dinv,
                                                const float* __restrict__ Wc0,
                                                const float* __restrict__ bc0,
                                                __half* __restrict__ tmpp2) {
    int wave = (blockIdx.x * 256 + threadIdx.x) >> 6;
    if (wave >= N_NODES) return;
    int lane = threadIdx.x & 63;
    int es = lane >> 2;
    int fq = lane & 3;
    // per-lane weight slice: Wc0[es][fq*4 .. fq*4+3] == Wc0 + lane*4 (coalesced)
    float4 wr = *reinterpret_cast<const float4*>(Wc0 + lane * 4);

    int s0 = row_start[wave], s1 = row_start[wave + 1];
    float a0 = 0.0f, a1 = 0.0f, a2 = 0.0f, a3 = 0.0f;
    for (int e = s0 + es; e < s1; e += 16) {
        int src = srcs[e];
        float2 rv = *(reinterpret_cast<const float2*>(
                          tmpp1 + (long long)src * HIDDEN) + fq);
        const __half2* h2 = reinterpret_cast<const __half2*>(&rv);
        float2 f0 = __half22float2(h2[0]);
        float2 f1 = __half22float2(h2[1]);
        a0 += f0.x; a1 += f0.y; a2 += f1.x; a3 += f1.y;
    }
#pragma unroll
    for (int m = 4; m <= 32; m <<= 1) {
        a0 += __shfl_xor(a0, m);
        a1 += __shfl_xor(a1, m);
        a2 += __shfl_xor(a2, m);
        a3 += __shfl_xor(a3, m);
    }
    // self term (same value in all es lanes)
    float2 sv = *(reinterpret_cast<const float2*>(
                      tmpp1 + (long long)wave * HIDDEN) + fq);
    const __half2* s2 = reinterpret_cast<const __half2*>(&sv);
    float2 f0 = __half22float2(s2[0]);
    float2 f1 = __half22float2(s2[1]);
    a0 += f0.x; a1 += f0.y; a2 += f1.x; a3 += f1.y;
    // broadcast t[es] to this lane: quadrant es>>2 lives in lane (es>>2), component es&3
    int sl = es >> 2;
    float tx = __shfl(a0, sl), ty = __shfl(a1, sl), tz = __shfl(a2, sl), tw = __shfl(a3, sl);
    int c = es & 3;
    float tk = (c == 0) ? tx : (c == 1) ? ty : (c == 2) ? tz : tw;
    // partial product for k=es, butterfly-sum over es -> all lanes get (t@W)[fq*4..+3]
    float p0 = tk * wr.x, p1 = tk * wr.y, p2 = tk * wr.z, p3 = tk * wr.w;
#pragma unroll
    for (int m = 4; m <= 32; m <<= 1) {
        p0 += __shfl_xor(p0, m);
        p1 += __shfl_xor(p1, m);
        p2 += __shfl_xor(p2, m);
        p3 += __shfl_xor(p3, m);
    }
    if (es == 0) {
        float di = dinv[wave];
        float4 bv = *(reinterpret_cast<const float4*>(bc0) + fq);
        float o0 = fmaxf(di * p0 + bv.x, 0.0f);
        float o1 = fmaxf(di * p1 + bv.y, 0.0f);
        float o2 = fmaxf(di * p2 + bv.z, 0.0f);
        float o3 = fmaxf(di * p3 + bv.w, 0.0f);
        __half2 pk[2];
        pk[0] = __floats2half2_rn(di * o0, di * o1);
        pk[1] = __floats2half2_rn(di * o2, di * o3);
        *reinterpret_cast<float2*>(tmpp2 + (long long)wave * HIDDEN + fq * 4) =
            *reinterpret_cast<const float2*>(pk);
    }
}

// ---- conv2 aggregation + register-weight transform + classifier + log_softmax (ZERO LDS)
__global__ __launch_bounds__(256) void k_aggr_o(const int* __restrict__ row_start,
                                                const int* __restrict__ srcs,
                                                const __half* __restrict__ tmpp2,
                                                const float* __restrict__ dinv,
                                                const float* __restrict__ Wc1,
                                                const float* __restrict__ bc1,
                                                const float* __restrict__ W2,
                                                const float* __restrict__ b2,
                                                float* __restrict__ out) {
    int wave = (blockIdx.x * 256 + threadIdx.x) >> 6;
    if (wave >= N_NODES) return;
    int lane = threadIdx.x & 63;
    int es = lane >> 2;
    int fq = lane & 3;
    float4 wr = *reinterpret_cast<const float4*>(Wc1 + lane * 4);
    // classifier slice: classes cs..cs+nc-1; lane holds W2[es][cs..cs+4]
    int cs = (fq < 2) ? fq * 5 : 10 + (fq - 2) * 4;
    int nc = (fq < 2) ? 5 : 4;
    float w2r[5], b2r[5];
#pragma unroll
    for (int i = 0; i < 5; ++i) {
        int cc = cs + i;
        int ccl = cc > 17 ? 17 : cc;
        w2r[i] = W2[es * N_CLASS + ccl];
        b2r[i] = b2[ccl];
    }

    int s0 = row_start[wave], s1 = row_start[wave + 1];
    float a0 = 0.0f, a1 = 0.0f, a2 = 0.0f, a3 = 0.0f;
    for (int e = s0 + es; e < s1; e += 16) {
        int src = srcs[e];
        float2 rv = *(reinterpret_cast<const float2*>(
                          tmpp2 + (long long)src * HIDDEN) + fq);
        const __half2* h2 = reinterpret_cast<const __half2*>(&rv);
        float2 f0 = __half22float2(h2[0]);
        float2 f1 = __half22float2(h2[1]);
        a0 += f0.x; a1 += f0.y; a2 += f1.x; a3 += f1.y;
    }
#pragma unroll
    for (int m = 4; m <= 32; m <<= 1) {
        a0 += __shfl_xor(a0, m);
        a1 += __shfl_xor(a1, m);
        a2 += __shfl_xor(a2, m);
        a3 += __shfl_xor(a3, m);
    }
    float2 sv = *(reinterpret_cast<const float2*>(
                      tmpp2 + (long long)wave * HIDDEN) + fq);
    const __half2* s2 = reinterpret_cast<const __half2*>(&sv);
    float2 f0 = __half22float2(s2[0]);
    float2 f1 = __half22float2(s2[1]);
    a0 += f0.x; a1 += f0.y; a2 += f1.x; a3 += f1.y;
    // transform: broadcast t[es], partial, butterfly
    int sl = es >> 2;
    float tx = __shfl(a0, sl), ty = __shfl(a1, sl), tz = __shfl(a2, sl), tw = __shfl(a3, sl);
    int c = es & 3;
    float tk = (c == 0) ? tx : (c == 1) ? ty : (c == 2) ? tz : tw;
    float p0 = tk * wr.x, p1 = tk * wr.y, p2 = tk * wr.z, p3 = tk * wr.w;
#pragma unroll
    for (int m = 4; m <= 32; m <<= 1) {
        p0 += __shfl_xor(p0, m);
        p1 += __shfl_xor(p1, m);
        p2 += __shfl_xor(p2, m);
        p3 += __shfl_xor(p3, m);
    }
    // h quadrant (all lanes have it after butterfly)
    float di = dinv[wave];
    float4 bv = *(reinterpret_cast<const float4*>(bc1) + fq);
    float h0 = fmaxf(di * p0 + bv.x, 0.0f);
    float h1 = fmaxf(di * p1 + bv.y, 0.0f);
    float h2v = fmaxf(di * p2 + bv.z, 0.0f);
    float h3v = fmaxf(di * p3 + bv.w, 0.0f);
    // classifier: broadcast h[es], partials for this lane's class slice, butterfly over es
    float hx = __shfl(h0, sl), hy = __shfl(h1, sl), hz = __shfl(h2v, sl), hw = __shfl(h3v, sl);
    float hk = (c == 0) ? hx : (c == 1) ? hy : (c == 2) ? hz : hw;
    float z0 = hk * w2r[0], z1 = hk * w2r[1], z2 = hk * w2r[2],
          z3 = hk * w2r[3], z4 = hk * w2r[4];
#pragma unroll
    for (int m = 4; m <= 32; m <<= 1) {
        z0 += __shfl_xor(z0, m);
        z1 += __shfl_xor(z1, m);
        z2 += __shfl_xor(z2, m);
        z3 += __shfl_xor(z3, m);
        z4 += __shfl_xor(z4, m);
    }
    z0 += b2r[0]; z1 += b2r[1]; z2 += b2r[2]; z3 += b2r[3];
    z4 = (nc == 5) ? (z4 + b2r[4]) : -1e30f;
    // log-sum-exp across the 4 fq lanes (each holds a disjoint class subset)
    float mx = fmaxf(fmaxf(fmaxf(z0, z1), fmaxf(z2, z3)), z4);
    mx = fmaxf(mx, __shfl_xor(mx, 1));
    mx = fmaxf(mx, __shfl_xor(mx, 2));
    float se = expf(z0 - mx) + expf(z1 - mx) + expf(z2 - mx) + expf(z3 - mx)
             + ((nc == 5) ? expf(z4 - mx) : 0.0f);
    se += __shfl_xor(se, 1);
    se += __shfl_xor(se, 2);
    float l = mx + logf(se);
    if (es == 0) {
        float* orow = out + (long long)wave * N_CLASS + cs;
        orow[0] = z0 - l;
        orow[1] = z1 - l;
        orow[2] = z2 - l;
        orow[3] = z3 - l;
        if (nc == 5) orow[4] = z4 - l;
    }
}

static inline char* align256(char* p) {
    return (char*)(((size_t)p + 255) & ~(size_t)255);
}

extern "C" void kernel_launch(void* const* d_in, const int* in_sizes, int n_in,
                              void* d_out, int out_size, void* d_ws, size_t ws_size,
                              hipStream_t stream) {
    const float* x   = (const float*)d_in[0];
    const int*   ei  = (const int*)d_in[1];
    const float* W1  = (const float*)d_in[2];
    const float* b1  = (const float*)d_in[3];
    const float* Wc0 = (const float*)d_in[4];
    const float* bc0 = (const float*)d_in[5];
    const float* Wc1 = (const float*)d_in[6];
    const float* bc1 = (const float*)d_in[7];
    const float* W2  = (const float*)d_in[8];
    const float* b2  = (const float*)d_in[9];
    float* out = (float*)d_out;

    long long E = (long long)in_sizes[1] / 2;
    int nt = (int)((E + TILE_B - 1) / TILE_B);

    char* p = (char*)d_ws;
    float* dinv    = (float*)p;          p = align256(p + sizeof(float) * N_NODES);
    int* row_start = (int*)p;            p = align256(p + sizeof(int) * (N_NODES + 1));
    int* bcnt      = (int*)p;            p = align256(p + sizeof(int) * NBKT);
    int* bkt_base  = (int*)p;            p = align256(p + sizeof(int) * (NBKT + 1));
    int* thist     = (int*)p;            p = align256(p + sizeof(int) * (size_t)nt * NBKT);
    int* tbase     = (int*)p;            p = align256(p + sizeof(int) * (size_t)nt * NBKT);
    int* pairs     = (int*)p;            p = align256(p + sizeof(int) * E);
    __half* tmpp1  = (__half*)p;         p = align256(p + sizeof(__half) * (size_t)N_NODES * HIDDEN);
    __half* tmpp2  = (__half*)p;         p = align256(p + sizeof(__half) * (size_t)N_NODES * HIDDEN);

    const int nblk_node = (N_NODES + 255) / 256;
    const int nblk_bcnt = (int)((E + 2 * TILE_B - 1) / (2 * TILE_B));
    const int nblk_aggr = (int)(((long long)N_NODES * 64 + 255) / 256);

    hipMemsetAsync(bcnt, 0, sizeof(int) * NBKT, stream);

    k_bcnt<<<nblk_bcnt, 512, 0, stream>>>(ei, E, nt, bcnt, thist);
    k_tscan<<<NBKT, 256, 0, stream>>>(thist, bcnt, nt, tbase, bkt_base);
    k_bucket<<<nt, 512, 0, stream>>>(ei, E, thist, tbase, pairs);
    k_csr<<<NBKT, 256, 0, stream>>>(bkt_base, pairs, row_start, dinv, (int)E);

    k_lin1h<<<nblk_node, 512, 0, stream>>>(x, W1, b1, dinv, tmpp1);

    k_aggr_t<<<nblk_aggr, 256, 0, stream>>>(row_start, pairs, tmpp1, dinv, Wc0, bc0, tmpp2);
    k_aggr_o<<<nblk_aggr, 256, 0, stream>>>(row_start, pairs, tmpp2, dinv, Wc1, bc1, W2, b2, out);
}

// Round 15
// 190.867 us; speedup vs baseline: 1.5113x; 1.1857x over previous
//
#include <hip/hip_runtime.h>
#include <hip/hip_fp16.h>
#include <math.h>

#define N_NODES 100000
#define F_IN    100
#define HIDDEN  16
#define N_CLASS 18

#define BKT_SHIFT 7
#define BKT_NODES 128                                   // nodes per bucket
#define NBKT ((N_NODES + BKT_NODES - 1) / BKT_NODES)    // 782
#define TILE_B 4096                                     // edges per split tile
#define SORT_CAP 5120                                   // max edges per bucket

// ---- inline edge dtype detection: int64 little-endian (values < 2^31) has all-zero odd words
__device__ __forceinline__ int detect64(const int* __restrict__ ei) {
    int z = 1;
#pragma unroll
    for (int i = 0; i < 16; ++i)
        if (ei[2 * i + 1] != 0) z = 0;
    return z;
}

__device__ __forceinline__ int edge_at(const int* __restrict__ ei, long long idx, int is64) {
    return is64 ? ei[2 * idx] : ei[idx];
}

// ---- per-tile bucket histograms (2 tiles of 4096 per block) + global bucket counts
__global__ __launch_bounds__(512) void k_bcnt(const int* __restrict__ ei, long long E,
                                              int nt,
                                              int* __restrict__ bcnt,
                                              int* __restrict__ thist) {
    __shared__ int hist0[NBKT];
    __shared__ int hist1[NBKT];
    int tid = threadIdx.x;
    for (int i = tid; i < NBKT; i += 512) { hist0[i] = 0; hist1[i] = 0; }
    __syncthreads();
    int is64 = detect64(ei);
    long long base = (long long)blockIdx.x * (2 * TILE_B);
    long long rem = E - base;
    int ntot = (int)((rem < (long long)(2 * TILE_B)) ? rem : (long long)(2 * TILE_B));
    int n0 = ntot < TILE_B ? ntot : TILE_B;
    int n1 = ntot - n0;
    for (int i = tid; i < n0; i += 512) {
        int d = edge_at(ei, E + base + i, is64);
        atomicAdd(&hist0[d >> BKT_SHIFT], 1);
    }
    for (int i = tid; i < n1; i += 512) {
        int d = edge_at(ei, E + base + TILE_B + i, is64);
        atomicAdd(&hist1[d >> BKT_SHIFT], 1);
    }
    __syncthreads();
    int t0 = blockIdx.x * 2, t1 = t0 + 1;
    for (int b = tid; b < NBKT; b += 512) {
        int c0 = hist0[b], c1 = hist1[b];
        thist[t0 * NBKT + b] = c0;
        if (n1 > 0) thist[t1 * NBKT + b] = c1;
        int c = c0 + c1;
        if (c) atomicAdd(&bcnt[b], c);
    }
}

// ---- per-bucket prefix over tiles (block b), with bkt_base reduction fused in
__global__ __launch_bounds__(256) void k_tscan(const int* __restrict__ thist,
                                               const int* __restrict__ bcnt,
                                               int nt,
                                               int* __restrict__ tbase,
                                               int* __restrict__ bkt_base) {
    __shared__ int ts[256];
    __shared__ int red[256];
    int b = blockIdx.x, tid = threadIdx.x;
    int partial = 0;
    for (int i = tid; i < b; i += 256) partial += bcnt[i];
    red[tid] = partial;
    __syncthreads();
    for (int off = 128; off > 0; off >>= 1) {
        if (tid < off) red[tid] += red[tid + off];
        __syncthreads();
    }
    int base = red[0];
    if (tid == 0) bkt_base[b] = base;
    int t0 = tid * 4;
    int c[4];
#pragma unroll
    for (int j = 0; j < 4; ++j) {
        int t = t0 + j;
        c[j] = (t < nt) ? thist[t * NBKT + b] : 0;
    }
    int s = c[0] + c[1] + c[2] + c[3];
    ts[tid] = s;
    __syncthreads();
    for (int off = 1; off < 256; off <<= 1) {
        int t = (tid >= off) ? ts[tid - off] : 0;
        __syncthreads();
        ts[tid] += t;
        __syncthreads();
    }
    int run = base + ts[tid] - s;
#pragma unroll
    for (int j = 0; j < 4; ++j) {
        int t = t0 + j;
        if (t < nt) { tbase[t * NBKT + b] = run; run += c[j]; }
    }
}

// ---- split: per-tile counting sort by bucket, deterministic positions (no atomics)
__global__ __launch_bounds__(512) void k_bucket(const int* __restrict__ ei, long long E,
                                                const int* __restrict__ thist,
                                                const int* __restrict__ tbase,
                                                int* __restrict__ pairs) {
    __shared__ int lbase[NBKT];
    __shared__ int gbase[NBKT];
    __shared__ int lcur[NBKT];
    __shared__ unsigned short perm[TILE_B];
    __shared__ int ts[512];
    int tid = threadIdx.x;
    int t = blockIdx.x;
    int is64 = detect64(ei);
    long long e0 = (long long)t * TILE_B;
    int n = (int)(((E - e0) < (long long)TILE_B) ? (E - e0) : (long long)TILE_B);

    int b0 = tid * 2;
    int h0 = (b0 + 0 < NBKT) ? thist[t * NBKT + b0 + 0] : 0;
    int h1 = (b0 + 1 < NBKT) ? thist[t * NBKT + b0 + 1] : 0;
    int tsum = h0 + h1;
    ts[tid] = tsum;
    for (int b = tid; b < NBKT; b += 512) gbase[b] = tbase[t * NBKT + b];
    __syncthreads();
    for (int off = 1; off < 512; off <<= 1) {
        int tv = (tid >= off) ? ts[tid - off] : 0;
        __syncthreads();
        ts[tid] += tv;
        __syncthreads();
    }
    int eb = ts[tid] - tsum;
    if (b0 + 0 < NBKT) { lbase[b0 + 0] = eb;      lcur[b0 + 0] = eb; }
    if (b0 + 1 < NBKT) { lbase[b0 + 1] = eb + h0; lcur[b0 + 1] = eb + h0; }
    __syncthreads();

    for (int i = tid; i < n; i += 512) {
        int d = edge_at(ei, E + e0 + i, is64);
        int l = atomicAdd(&lcur[d >> BKT_SHIFT], 1);
        perm[l] = (unsigned short)i;
    }
    __syncthreads();

    for (int k = tid; k < n; k += 512) {
        int i = perm[k];
        int s = edge_at(ei, e0 + i, is64);
        int d = edge_at(ei, E + e0 + i, is64);
        int b = d >> BKT_SHIFT;
        int pos = gbase[b] + (k - lbase[b]);
        pairs[pos] = s | ((d & (BKT_NODES - 1)) << 17);
    }
}

// ---- fused CSR finalize: per bucket -> per-node counts, dinv, row_start, in-place sort
__global__ __launch_bounds__(256) void k_csr(const int* __restrict__ bkt_base,
                                             int* __restrict__ pairs,
                                             int* __restrict__ row_start,
                                             float* __restrict__ dinv,
                                             int Ei) {
    __shared__ int stage[SORT_CAP];
    __shared__ int lc[BKT_NODES];
    __shared__ int rs[BKT_NODES];
    int bk = blockIdx.x, tid = threadIdx.x;
    int i0 = bkt_base[bk];
    int i1 = (bk == NBKT - 1) ? Ei : bkt_base[bk + 1];
    int m = i1 - i0;
    if (tid < BKT_NODES) lc[tid] = 0;
    __syncthreads();
    for (int i = tid; i < m; i += 256) {
        int v = pairs[i0 + i];
        stage[i] = v;
        atomicAdd(&lc[v >> 17], 1);
    }
    __syncthreads();
    if (tid < BKT_NODES) rs[tid] = lc[tid];
    __syncthreads();
    for (int off = 1; off < BKT_NODES; off <<= 1) {
        int t = (tid >= off && tid < BKT_NODES) ? rs[tid - off] : 0;
        __syncthreads();
        if (tid < BKT_NODES) rs[tid] += t;
        __syncthreads();
    }
    int node = bk * BKT_NODES + tid;
    int ex = 0;
    if (tid < BKT_NODES) {
        int c = lc[tid];
        ex = rs[tid] - c;
        if (node < N_NODES) {
            row_start[node] = i0 + ex;
            dinv[node] = rsqrtf((float)c + 1.0f);
        }
    }
    if (bk == NBKT - 1 && tid == 0) row_start[N_NODES] = i1;
    __syncthreads();
    if (tid < BKT_NODES) lc[tid] = ex;
    __syncthreads();
    for (int i = tid; i < m; i += 256) {
        int v = stage[i];
        int pos = atomicAdd(&lc[v >> 17], 1);
        pairs[i0 + pos] = v & 0x1FFFF;
    }
}

// ---- fused split-K: tmpp = fp16( dinv * ( relu(x@W1+b1) @ Wc0 ) ); 2 threads/node
__global__ __launch_bounds__(512) void k_lin1f(const float* __restrict__ x,
                                               const float* __restrict__ W1,
                                               const float* __restrict__ b1,
                                               const float* __restrict__ Wc0,
                                               const float* __restrict__ dinv,
                                               __half* __restrict__ tmpp) {
    __shared__ float sW[F_IN * HIDDEN];
    __shared__ float sb[HIDDEN];
    __shared__ float sW2[HIDDEN * HIDDEN];
    for (int i = threadIdx.x; i < F_IN * HIDDEN; i += 512) sW[i] = W1[i];
    if (threadIdx.x < HIDDEN) sb[threadIdx.x] = b1[threadIdx.x];
    if (threadIdx.x >= 32 && threadIdx.x < 32 + HIDDEN * HIDDEN)
        sW2[threadIdx.x - 32] = Wc0[threadIdx.x - 32];
    __syncthreads();
    int node = blockIdx.x * 256 + (threadIdx.x >> 1);
    int half = threadIdx.x & 1;
    if (node >= N_NODES) return;

    float acc[HIDDEN];
#pragma unroll
    for (int j = 0; j < HIDDEN; ++j) acc[j] = half ? 0.0f : sb[j];

    const float4* x4 = reinterpret_cast<const float4*>(x + (long long)node * F_IN);
    int k40 = half ? 13 : 0;
    int k41 = half ? 25 : 13;
    for (int k4 = k40; k4 < k41; ++k4) {
        float4 xv = x4[k4];
        const float* w = &sW[k4 * 4 * HIDDEN];
#pragma unroll
        for (int j = 0; j < HIDDEN; ++j) {
            acc[j] += xv.x * w[0 * HIDDEN + j];
            acc[j] += xv.y * w[1 * HIDDEN + j];
            acc[j] += xv.z * w[2 * HIDDEN + j];
            acc[j] += xv.w * w[3 * HIDDEN + j];
        }
    }
#pragma unroll
    for (int j = 0; j < HIDDEN; ++j) {
        acc[j] += __shfl_xor(acc[j], 1);
        acc[j] = fmaxf(acc[j], 0.0f);
    }
    float out[8];
#pragma unroll
    for (int j = 0; j < 8; ++j) out[j] = 0.0f;
    int j0 = half * 8;
#pragma unroll
    for (int k = 0; k < HIDDEN; ++k) {
        float hk = acc[k];
#pragma unroll
        for (int j = 0; j < 8; ++j) out[j] += hk * sW2[k * HIDDEN + j0 + j];
    }
    float di = dinv[node];
    __half2 packed[4];
#pragma unroll
    for (int j = 0; j < 4; ++j)
        packed[j] = __floats2half2_rn(di * out[2 * j], di * out[2 * j + 1]);
    *reinterpret_cast<float4*>(tmpp + (long long)node * HIDDEN + half * 8) =
        *reinterpret_cast<const float4*>(packed);
}

// ---- tmp' = fp16( dinv[i] * (h @ W) )
__global__ __launch_bounds__(256) void k_mm16(const float* __restrict__ h,
                                              const float* __restrict__ W,
                                              const float* __restrict__ dinv,
                                              __half* __restrict__ tmpp) {
    __shared__ float sW[HIDDEN * HIDDEN];
    if (threadIdx.x < HIDDEN * HIDDEN) sW[threadIdx.x] = W[threadIdx.x];
    __syncthreads();
    int node = blockIdx.x * 256 + threadIdx.x;
    if (node >= N_NODES) return;

    float hv[HIDDEN];
    const float4* hr = reinterpret_cast<const float4*>(h + (long long)node * HIDDEN);
#pragma unroll
    for (int q = 0; q < HIDDEN / 4; ++q) {
        float4 v = hr[q];
        hv[q * 4 + 0] = v.x; hv[q * 4 + 1] = v.y;
        hv[q * 4 + 2] = v.z; hv[q * 4 + 3] = v.w;
    }
    float di = dinv[node];
    float out[HIDDEN];
#pragma unroll
    for (int j = 0; j < HIDDEN; ++j) out[j] = 0.0f;
#pragma unroll
    for (int k = 0; k < HIDDEN; ++k) {
        float hk = hv[k];
#pragma unroll
        for (int j = 0; j < HIDDEN; ++j) out[j] += hk * sW[k * HIDDEN + j];
    }
    __half2 packed[8];
#pragma unroll
    for (int j = 0; j < 8; ++j)
        packed[j] = __floats2half2_rn(di * out[2 * j], di * out[2 * j + 1]);
    float4* tp = reinterpret_cast<float4*>(tmpp + (long long)node * HIDDEN);
    const float4* ps = reinterpret_cast<const float4*>(packed);
    tp[0] = ps[0];
    tp[1] = ps[1];
}

// ---- wave-per-node register pull, 4 lanes/row; 2-deep hoisted loads; fused epilogue
// h[n] = relu(dinv[n]*(sum_src tmpp[src] + tmpp[n]) + b)
__global__ __launch_bounds__(256) void k_aggr(const int* __restrict__ row_start,
                                              const int* __restrict__ srcs,
                                              const __half* __restrict__ tmpp,
                                              const float* __restrict__ dinv,
                                              const float* __restrict__ b,
                                              float* __restrict__ h) {
    int wave = (blockIdx.x * 256 + threadIdx.x) >> 6;   // node id
    if (wave >= N_NODES) return;
    int lane = threadIdx.x & 63;
    int es = lane >> 2;        // edge slot 0..15
    int fq = lane & 3;         // feature quarter (4 halves = 8 B)

    int s0 = row_start[wave], s1 = row_start[wave + 1];
    float a0 = 0.0f, a1 = 0.0f, a2 = 0.0f, a3 = 0.0f;
    const float2* t2 = reinterpret_cast<const float2*>(tmpp);

    // 2-deep software pipeline: both edge-id loads then both gathers per trip,
    // tail handled by clamp+mask (no extra control flow, loads stay hoisted)
    for (int e = s0 + es; e < s1; e += 32) {
        int eb  = e + 16;
        int ebc = (eb < s1) ? eb : (s1 - 1);
        float mb = (eb < s1) ? 1.0f : 0.0f;
        int sa = srcs[e];
        int sb = srcs[ebc];
        float2 ra = t2[(long long)sa * 4 + fq];
        float2 rb = t2[(long long)sb * 4 + fq];
        const __half2* ha = reinterpret_cast<const __half2*>(&ra);
        const __half2* hb = reinterpret_cast<const __half2*>(&rb);
        float2 fa0 = __half22float2(ha[0]);
        float2 fa1 = __half22float2(ha[1]);
        float2 fb0 = __half22float2(hb[0]);
        float2 fb1 = __half22float2(hb[1]);
        a0 += fa0.x + mb * fb0.x;
        a1 += fa0.y + mb * fb0.y;
        a2 += fa1.x + mb * fb1.x;
        a3 += fa1.y + mb * fb1.y;
    }
#pragma unroll
    for (int m = 4; m <= 32; m <<= 1) {
        a0 += __shfl_xor(a0, m);
        a1 += __shfl_xor(a1, m);
        a2 += __shfl_xor(a2, m);
        a3 += __shfl_xor(a3, m);
    }
    if (es == 0) {
        float2 sv = t2[(long long)wave * 4 + fq];
        const __half2* s2 = reinterpret_cast<const __half2*>(&sv);
        float2 f0 = __half22float2(s2[0]);
        float2 f1 = __half22float2(s2[1]);
        float di = dinv[wave];
        float4 bv = *(reinterpret_cast<const float4*>(b) + fq);
        float4 o;
        o.x = fmaxf(di * (a0 + f0.x) + bv.x, 0.0f);
        o.y = fmaxf(di * (a1 + f0.y) + bv.y, 0.0f);
        o.z = fmaxf(di * (a2 + f1.x) + bv.z, 0.0f);
        o.w = fmaxf(di * (a3 + f1.y) + bv.w, 0.0f);
        *(reinterpret_cast<float4*>(h + (long long)wave * HIDDEN) + fq) = o;
    }
}

// ---- out = log_softmax(h @ W2 + b2)
__global__ __launch_bounds__(256) void k_out(const float* __restrict__ h,
                                             const float* __restrict__ W2,
                                             const float* __restrict__ b2,
                                             float* __restrict__ out) {
    __shared__ float sW[HIDDEN * N_CLASS];
    __shared__ float sb[N_CLASS];
    for (int i = threadIdx.x; i < HIDDEN * N_CLASS; i += 256) sW[i] = W2[i];
    if (threadIdx.x < N_CLASS) sb[threadIdx.x] = b2[threadIdx.x];
    __syncthreads();
    int node = blockIdx.x * 256 + threadIdx.x;
    if (node >= N_NODES) return;

    float hv[HIDDEN];
    const float4* hr = reinterpret_cast<const float4*>(h + (long long)node * HIDDEN);
#pragma unroll
    for (int q = 0; q < HIDDEN / 4; ++q) {
        float4 v = hr[q];
        hv[q * 4 + 0] = v.x; hv[q * 4 + 1] = v.y;
        hv[q * 4 + 2] = v.z; hv[q * 4 + 3] = v.w;
    }
    float z[N_CLASS];
#pragma unroll
    for (int c = 0; c < N_CLASS; ++c) z[c] = sb[c];
#pragma unroll
    for (int k = 0; k < HIDDEN; ++k) {
        float hk = hv[k];
#pragma unroll
        for (int c = 0; c < N_CLASS; ++c) z[c] += hk * sW[k * N_CLASS + c];
    }
    float m = z[0];
#pragma unroll
    for (int c = 1; c < N_CLASS; ++c) m = fmaxf(m, z[c]);
    float ssum = 0.0f;
#pragma unroll
    for (int c = 0; c < N_CLASS; ++c) ssum += expf(z[c] - m);
    float l = m + logf(ssum);
    float* orow = out + (long long)node * N_CLASS;
#pragma unroll
    for (int c = 0; c < N_CLASS; ++c) orow[c] = z[c] - l;
}

static inline char* align256(char* p) {
    return (char*)(((size_t)p + 255) & ~(size_t)255);
}

extern "C" void kernel_launch(void* const* d_in, const int* in_sizes, int n_in,
                              void* d_out, int out_size, void* d_ws, size_t ws_size,
                              hipStream_t stream) {
    const float* x   = (const float*)d_in[0];
    const int*   ei  = (const int*)d_in[1];
    const float* W1  = (const float*)d_in[2];
    const float* b1  = (const float*)d_in[3];
    const float* Wc0 = (const float*)d_in[4];
    const float* bc0 = (const float*)d_in[5];
    const float* Wc1 = (const float*)d_in[6];
    const float* bc1 = (const float*)d_in[7];
    const float* W2  = (const float*)d_in[8];
    const float* b2  = (const float*)d_in[9];
    float* out = (float*)d_out;

    long long E = (long long)in_sizes[1] / 2;
    int nt = (int)((E + TILE_B - 1) / TILE_B);

    char* p = (char*)d_ws;
    float* dinv    = (float*)p;          p = align256(p + sizeof(float) * N_NODES);
    int* row_start = (int*)p;            p = align256(p + sizeof(int) * (N_NODES + 1));
    int* bcnt      = (int*)p;            p = align256(p + sizeof(int) * NBKT);
    int* bkt_base  = (int*)p;            p = align256(p + sizeof(int) * (NBKT + 1));
    int* thist     = (int*)p;            p = align256(p + sizeof(int) * (size_t)nt * NBKT);
    int* tbase     = (int*)p;            p = align256(p + sizeof(int) * (size_t)nt * NBKT);
    int* pairs     = (int*)p;            p = align256(p + sizeof(int) * E);
    float* h       = (float*)p;          p = align256(p + sizeof(float) * (size_t)N_NODES * HIDDEN);
    __half* tmpp   = (__half*)p;         p = align256(p + sizeof(__half) * (size_t)N_NODES * HIDDEN);

    const int nblk_node = (N_NODES + 255) / 256;
    const int nblk_bcnt = (int)((E + 2 * TILE_B - 1) / (2 * TILE_B));
    const int nblk_aggr = (int)(((long long)N_NODES * 64 + 255) / 256);

    hipMemsetAsync(bcnt, 0, sizeof(int) * NBKT, stream);

    k_bcnt<<<nblk_bcnt, 512, 0, stream>>>(ei, E, nt, bcnt, thist);
    k_tscan<<<NBKT, 256, 0, stream>>>(thist, bcnt, nt, tbase, bkt_base);
    k_bucket<<<nt, 512, 0, stream>>>(ei, E, thist, tbase, pairs);
    k_csr<<<NBKT, 256, 0, stream>>>(bkt_base, pairs, row_start, dinv, (int)E);

    // conv 1 (lin1 fused into the dense transform)
    k_lin1f<<<nblk_node, 512, 0, stream>>>(x, W1, b1, Wc0, dinv, tmpp);
    k_aggr<<<nblk_aggr, 256, 0, stream>>>(row_start, pairs, tmpp, dinv, bc0, h);

    // conv 2
    k_mm16<<<nblk_node, 256, 0, stream>>>(h, Wc1, dinv, tmpp);
    k_aggr<<<nblk_aggr, 256, 0, stream>>>(row_start, pairs, tmpp, dinv, bc1, h);

    k_out<<<nblk_node, 256, 0, stream>>>(h, W2, b2, out);
}

// Round 16
// 189.074 us; speedup vs baseline: 1.5257x; 1.0095x over previous
//
#include <hip/hip_runtime.h>
#include <hip/hip_fp16.h>
#include <math.h>

#define N_NODES 100000
#define F_IN    100
#define HIDDEN  16
#define N_CLASS 18

#define BKT_SHIFT 7
#define BKT_NODES 128                                   // nodes per bucket
#define NBKT ((N_NODES + BKT_NODES - 1) / BKT_NODES)    // 782
#define TILE_B 4096                                     // edges per split tile
#define SORT_CAP 5120                                   // max edges per bucket

// ---- inline edge dtype detection: int64 little-endian (values < 2^31) has all-zero odd words
__device__ __forceinline__ int detect64(const int* __restrict__ ei) {
    int z = 1;
#pragma unroll
    for (int i = 0; i < 16; ++i)
        if (ei[2 * i + 1] != 0) z = 0;
    return z;
}

__device__ __forceinline__ int edge_at(const int* __restrict__ ei, long long idx, int is64) {
    return is64 ? ei[2 * idx] : ei[idx];
}

// ---- zero the 782-int bucket-count array (replaces hipMemsetAsync's 39us blit)
__global__ __launch_bounds__(1024) void k_zero(int* __restrict__ bcnt) {
    int i = threadIdx.x;
    if (i < NBKT) bcnt[i] = 0;
}

// ---- per-tile bucket histograms (2 tiles of 4096 per block) + global bucket counts
__global__ __launch_bounds__(512) void k_bcnt(const int* __restrict__ ei, long long E,
                                              int nt,
                                              int* __restrict__ bcnt,
                                              int* __restrict__ thist) {
    __shared__ int hist0[NBKT];
    __shared__ int hist1[NBKT];
    int tid = threadIdx.x;
    for (int i = tid; i < NBKT; i += 512) { hist0[i] = 0; hist1[i] = 0; }
    __syncthreads();
    int is64 = detect64(ei);
    long long base = (long long)blockIdx.x * (2 * TILE_B);
    long long rem = E - base;
    int ntot = (int)((rem < (long long)(2 * TILE_B)) ? rem : (long long)(2 * TILE_B));
    int n0 = ntot < TILE_B ? ntot : TILE_B;
    int n1 = ntot - n0;
    for (int i = tid; i < n0; i += 512) {
        int d = edge_at(ei, E + base + i, is64);
        atomicAdd(&hist0[d >> BKT_SHIFT], 1);
    }
    for (int i = tid; i < n1; i += 512) {
        int d = edge_at(ei, E + base + TILE_B + i, is64);
        atomicAdd(&hist1[d >> BKT_SHIFT], 1);
    }
    __syncthreads();
    int t0 = blockIdx.x * 2, t1 = t0 + 1;
    for (int b = tid; b < NBKT; b += 512) {
        int c0 = hist0[b], c1 = hist1[b];
        thist[t0 * NBKT + b] = c0;
        if (n1 > 0) thist[t1 * NBKT + b] = c1;
        int c = c0 + c1;
        if (c) atomicAdd(&bcnt[b], c);
    }
}

// ---- per-bucket prefix over tiles (block b), with bkt_base reduction fused in
__global__ __launch_bounds__(256) void k_tscan(const int* __restrict__ thist,
                                               const int* __restrict__ bcnt,
                                               int nt,
                                               int* __restrict__ tbase,
                                               int* __restrict__ bkt_base) {
    __shared__ int ts[256];
    __shared__ int red[256];
    int b = blockIdx.x, tid = threadIdx.x;
    int partial = 0;
    for (int i = tid; i < b; i += 256) partial += bcnt[i];
    red[tid] = partial;
    __syncthreads();
    for (int off = 128; off > 0; off >>= 1) {
        if (tid < off) red[tid] += red[tid + off];
        __syncthreads();
    }
    int base = red[0];
    if (tid == 0) bkt_base[b] = base;
    int t0 = tid * 4;
    int c[4];
#pragma unroll
    for (int j = 0; j < 4; ++j) {
        int t = t0 + j;
        c[j] = (t < nt) ? thist[t * NBKT + b] : 0;
    }
    int s = c[0] + c[1] + c[2] + c[3];
    ts[tid] = s;
    __syncthreads();
    for (int off = 1; off < 256; off <<= 1) {
        int t = (tid >= off) ? ts[tid - off] : 0;
        __syncthreads();
        ts[tid] += t;
        __syncthreads();
    }
    int run = base + ts[tid] - s;
#pragma unroll
    for (int j = 0; j < 4; ++j) {
        int t = t0 + j;
        if (t < nt) { tbase[t * NBKT + b] = run; run += c[j]; }
    }
}

// ---- split: per-tile counting sort by bucket, deterministic positions (no atomics)
__global__ __launch_bounds__(512) void k_bucket(const int* __restrict__ ei, long long E,
                                                const int* __restrict__ thist,
                                                const int* __restrict__ tbase,
                                                int* __restrict__ pairs) {
    __shared__ int lbase[NBKT];
    __shared__ int gbase[NBKT];
    __shared__ int lcur[NBKT];
    __shared__ unsigned short perm[TILE_B];
    __shared__ int ts[512];
    int tid = threadIdx.x;
    int t = blockIdx.x;
    int is64 = detect64(ei);
    long long e0 = (long long)t * TILE_B;
    int n = (int)(((E - e0) < (long long)TILE_B) ? (E - e0) : (long long)TILE_B);

    int b0 = tid * 2;
    int h0 = (b0 + 0 < NBKT) ? thist[t * NBKT + b0 + 0] : 0;
    int h1 = (b0 + 1 < NBKT) ? thist[t * NBKT + b0 + 1] : 0;
    int tsum = h0 + h1;
    ts[tid] = tsum;
    for (int b = tid; b < NBKT; b += 512) gbase[b] = tbase[t * NBKT + b];
    __syncthreads();
    for (int off = 1; off < 512; off <<= 1) {
        int tv = (tid >= off) ? ts[tid - off] : 0;
        __syncthreads();
        ts[tid] += tv;
        __syncthreads();
    }
    int eb = ts[tid] - tsum;
    if (b0 + 0 < NBKT) { lbase[b0 + 0] = eb;      lcur[b0 + 0] = eb; }
    if (b0 + 1 < NBKT) { lbase[b0 + 1] = eb + h0; lcur[b0 + 1] = eb + h0; }
    __syncthreads();

    for (int i = tid; i < n; i += 512) {
        int d = edge_at(ei, E + e0 + i, is64);
        int l = atomicAdd(&lcur[d >> BKT_SHIFT], 1);
        perm[l] = (unsigned short)i;
    }
    __syncthreads();

    for (int k = tid; k < n; k += 512) {
        int i = perm[k];
        int s = edge_at(ei, e0 + i, is64);
        int d = edge_at(ei, E + e0 + i, is64);
        int b = d >> BKT_SHIFT;
        int pos = gbase[b] + (k - lbase[b]);
        pairs[pos] = s | ((d & (BKT_NODES - 1)) << 17);
    }
}

// ---- fused CSR finalize: per bucket -> per-node counts, dinv, row_start, in-place sort
__global__ __launch_bounds__(256) void k_csr(const int* __restrict__ bkt_base,
                                             int* __restrict__ pairs,
                                             int* __restrict__ row_start,
                                             float* __restrict__ dinv,
                                             int Ei) {
    __shared__ int stage[SORT_CAP];
    __shared__ int lc[BKT_NODES];
    __shared__ int rs[BKT_NODES];
    int bk = blockIdx.x, tid = threadIdx.x;
    int i0 = bkt_base[bk];
    int i1 = (bk == NBKT - 1) ? Ei : bkt_base[bk + 1];
    int m = i1 - i0;
    if (tid < BKT_NODES) lc[tid] = 0;
    __syncthreads();
    for (int i = tid; i < m; i += 256) {
        int v = pairs[i0 + i];
        stage[i] = v;
        atomicAdd(&lc[v >> 17], 1);
    }
    __syncthreads();
    if (tid < BKT_NODES) rs[tid] = lc[tid];
    __syncthreads();
    for (int off = 1; off < BKT_NODES; off <<= 1) {
        int t = (tid >= off && tid < BKT_NODES) ? rs[tid - off] : 0;
        __syncthreads();
        if (tid < BKT_NODES) rs[tid] += t;
        __syncthreads();
    }
    int node = bk * BKT_NODES + tid;
    int ex = 0;
    if (tid < BKT_NODES) {
        int c = lc[tid];
        ex = rs[tid] - c;
        if (node < N_NODES) {
            row_start[node] = i0 + ex;
            dinv[node] = rsqrtf((float)c + 1.0f);
        }
    }
    if (bk == NBKT - 1 && tid == 0) row_start[N_NODES] = i1;
    __syncthreads();
    if (tid < BKT_NODES) lc[tid] = ex;
    __syncthreads();
    for (int i = tid; i < m; i += 256) {
        int v = stage[i];
        int pos = atomicAdd(&lc[v >> 17], 1);
        pairs[i0 + pos] = v & 0x1FFFF;
    }
}

// ---- fused split-K: tmpp = fp16( dinv * ( relu(x@W1+b1) @ Wc0 ) ); 2 threads/node
__global__ __launch_bounds__(512) void k_lin1f(const float* __restrict__ x,
                                               const float* __restrict__ W1,
                                               const float* __restrict__ b1,
                                               const float* __restrict__ Wc0,
                                               const float* __restrict__ dinv,
                                               __half* __restrict__ tmpp) {
    __shared__ float sW[F_IN * HIDDEN];
    __shared__ float sb[HIDDEN];
    __shared__ float sW2[HIDDEN * HIDDEN];
    for (int i = threadIdx.x; i < F_IN * HIDDEN; i += 512) sW[i] = W1[i];
    if (threadIdx.x < HIDDEN) sb[threadIdx.x] = b1[threadIdx.x];
    if (threadIdx.x >= 32 && threadIdx.x < 32 + HIDDEN * HIDDEN)
        sW2[threadIdx.x - 32] = Wc0[threadIdx.x - 32];
    __syncthreads();
    int node = blockIdx.x * 256 + (threadIdx.x >> 1);
    int half = threadIdx.x & 1;
    if (node >= N_NODES) return;

    float acc[HIDDEN];
#pragma unroll
    for (int j = 0; j < HIDDEN; ++j) acc[j] = half ? 0.0f : sb[j];

    const float4* x4 = reinterpret_cast<const float4*>(x + (long long)node * F_IN);
    int k40 = half ? 13 : 0;
    int k41 = half ? 25 : 13;
    for (int k4 = k40; k4 < k41; ++k4) {
        float4 xv = x4[k4];
        const float* w = &sW[k4 * 4 * HIDDEN];
#pragma unroll
        for (int j = 0; j < HIDDEN; ++j) {
            acc[j] += xv.x * w[0 * HIDDEN + j];
            acc[j] += xv.y * w[1 * HIDDEN + j];
            acc[j] += xv.z * w[2 * HIDDEN + j];
            acc[j] += xv.w * w[3 * HIDDEN + j];
        }
    }
#pragma unroll
    for (int j = 0; j < HIDDEN; ++j) {
        acc[j] += __shfl_xor(acc[j], 1);
        acc[j] = fmaxf(acc[j], 0.0f);
    }
    float out[8];
#pragma unroll
    for (int j = 0; j < 8; ++j) out[j] = 0.0f;
    int j0 = half * 8;
#pragma unroll
    for (int k = 0; k < HIDDEN; ++k) {
        float hk = acc[k];
#pragma unroll
        for (int j = 0; j < 8; ++j) out[j] += hk * sW2[k * HIDDEN + j0 + j];
    }
    float di = dinv[node];
    __half2 packed[4];
#pragma unroll
    for (int j = 0; j < 4; ++j)
        packed[j] = __floats2half2_rn(di * out[2 * j], di * out[2 * j + 1]);
    *reinterpret_cast<float4*>(tmpp + (long long)node * HIDDEN + half * 8) =
        *reinterpret_cast<const float4*>(packed);
}

// ---- tmp' = fp16( dinv[i] * (h @ W) )
__global__ __launch_bounds__(256) void k_mm16(const float* __restrict__ h,
                                              const float* __restrict__ W,
                                              const float* __restrict__ dinv,
                                              __half* __restrict__ tmpp) {
    __shared__ float sW[HIDDEN * HIDDEN];
    if (threadIdx.x < HIDDEN * HIDDEN) sW[threadIdx.x] = W[threadIdx.x];
    __syncthreads();
    int node = blockIdx.x * 256 + threadIdx.x;
    if (node >= N_NODES) return;

    float hv[HIDDEN];
    const float4* hr = reinterpret_cast<const float4*>(h + (long long)node * HIDDEN);
#pragma unroll
    for (int q = 0; q < HIDDEN / 4; ++q) {
        float4 v = hr[q];
        hv[q * 4 + 0] = v.x; hv[q * 4 + 1] = v.y;
        hv[q * 4 + 2] = v.z; hv[q * 4 + 3] = v.w;
    }
    float di = dinv[node];
    float out[HIDDEN];
#pragma unroll
    for (int j = 0; j < HIDDEN; ++j) out[j] = 0.0f;
#pragma unroll
    for (int k = 0; k < HIDDEN; ++k) {
        float hk = hv[k];
#pragma unroll
        for (int j = 0; j < HIDDEN; ++j) out[j] += hk * sW[k * HIDDEN + j];
    }
    __half2 packed[8];
#pragma unroll
    for (int j = 0; j < 8; ++j)
        packed[j] = __floats2half2_rn(di * out[2 * j], di * out[2 * j + 1]);
    float4* tp = reinterpret_cast<float4*>(tmpp + (long long)node * HIDDEN);
    const float4* ps = reinterpret_cast<const float4*>(packed);
    tp[0] = ps[0];
    tp[1] = ps[1];
}

// ---- wave-per-node register pull, 4 lanes/row; 2-deep hoisted loads; fused epilogue
// h[n] = relu(dinv[n]*(sum_src tmpp[src] + tmpp[n]) + b)
__global__ __launch_bounds__(256) void k_aggr(const int* __restrict__ row_start,
                                              const int* __restrict__ srcs,
                                              const __half* __restrict__ tmpp,
                                              const float* __restrict__ dinv,
                                              const float* __restrict__ b,
                                              float* __restrict__ h) {
    int wave = (blockIdx.x * 256 + threadIdx.x) >> 6;   // node id
    if (wave >= N_NODES) return;
    int lane = threadIdx.x & 63;
    int es = lane >> 2;        // edge slot 0..15
    int fq = lane & 3;         // feature quarter (4 halves = 8 B)

    int s0 = row_start[wave], s1 = row_start[wave + 1];
    float a0 = 0.0f, a1 = 0.0f, a2 = 0.0f, a3 = 0.0f;
    const float2* t2 = reinterpret_cast<const float2*>(tmpp);

    // 2-deep software pipeline: both edge-id loads then both gathers per trip,
    // tail handled by clamp+mask (no extra control flow, loads stay hoisted)
    for (int e = s0 + es; e < s1; e += 32) {
        int eb  = e + 16;
        int ebc = (eb < s1) ? eb : (s1 - 1);
        float mb = (eb < s1) ? 1.0f : 0.0f;
        int sa = srcs[e];
        int sb = srcs[ebc];
        float2 ra = t2[(long long)sa * 4 + fq];
        float2 rb = t2[(long long)sb * 4 + fq];
        const __half2* ha = reinterpret_cast<const __half2*>(&ra);
        const __half2* hb = reinterpret_cast<const __half2*>(&rb);
        float2 fa0 = __half22float2(ha[0]);
        float2 fa1 = __half22float2(ha[1]);
        float2 fb0 = __half22float2(hb[0]);
        float2 fb1 = __half22float2(hb[1]);
        a0 += fa0.x + mb * fb0.x;
        a1 += fa0.y + mb * fb0.y;
        a2 += fa1.x + mb * fb1.x;
        a3 += fa1.y + mb * fb1.y;
    }
#pragma unroll
    for (int m = 4; m <= 32; m <<= 1) {
        a0 += __shfl_xor(a0, m);
        a1 += __shfl_xor(a1, m);
        a2 += __shfl_xor(a2, m);
        a3 += __shfl_xor(a3, m);
    }
    if (es == 0) {
        float2 sv = t2[(long long)wave * 4 + fq];
        const __half2* s2 = reinterpret_cast<const __half2*>(&sv);
        float2 f0 = __half22float2(s2[0]);
        float2 f1 = __half22float2(s2[1]);
        float di = dinv[wave];
        float4 bv = *(reinterpret_cast<const float4*>(b) + fq);
        float4 o;
        o.x = fmaxf(di * (a0 + f0.x) + bv.x, 0.0f);
        o.y = fmaxf(di * (a1 + f0.y) + bv.y, 0.0f);
        o.z = fmaxf(di * (a2 + f1.x) + bv.z, 0.0f);
        o.w = fmaxf(di * (a3 + f1.y) + bv.w, 0.0f);
        *(reinterpret_cast<float4*>(h + (long long)wave * HIDDEN) + fq) = o;
    }
}

// ---- out = log_softmax(h @ W2 + b2)
__global__ __launch_bounds__(256) void k_out(const float* __restrict__ h,
                                             const float* __restrict__ W2,
                                             const float* __restrict__ b2,
                                             float* __restrict__ out) {
    __shared__ float sW[HIDDEN * N_CLASS];
    __shared__ float sb[N_CLASS];
    for (int i = threadIdx.x; i < HIDDEN * N_CLASS; i += 256) sW[i] = W2[i];
    if (threadIdx.x < N_CLASS) sb[threadIdx.x] = b2[threadIdx.x];
    __syncthreads();
    int node = blockIdx.x * 256 + threadIdx.x;
    if (node >= N_NODES) return;

    float hv[HIDDEN];
    const float4* hr = reinterpret_cast<const float4*>(h + (long long)node * HIDDEN);
#pragma unroll
    for (int q = 0; q < HIDDEN / 4; ++q) {
        float4 v = hr[q];
        hv[q * 4 + 0] = v.x; hv[q * 4 + 1] = v.y;
        hv[q * 4 + 2] = v.z; hv[q * 4 + 3] = v.w;
    }
    float z[N_CLASS];
#pragma unroll
    for (int c = 0; c < N_CLASS; ++c) z[c] = sb[c];
#pragma unroll
    for (int k = 0; k < HIDDEN; ++k) {
        float hk = hv[k];
#pragma unroll
        for (int c = 0; c < N_CLASS; ++c) z[c] += hk * sW[k * N_CLASS + c];
    }
    float m = z[0];
#pragma unroll
    for (int c = 1; c < N_CLASS; ++c) m = fmaxf(m, z[c]);
    float ssum = 0.0f;
#pragma unroll
    for (int c = 0; c < N_CLASS; ++c) ssum += expf(z[c] - m);
    float l = m + logf(ssum);
    float* orow = out + (long long)node * N_CLASS;
#pragma unroll
    for (int c = 0; c < N_CLASS; ++c) orow[c] = z[c] - l;
}

static inline char* align256(char* p) {
    return (char*)(((size_t)p + 255) & ~(size_t)255);
}

extern "C" void kernel_launch(void* const* d_in, const int* in_sizes, int n_in,
                              void* d_out, int out_size, void* d_ws, size_t ws_size,
                              hipStream_t stream) {
    const float* x   = (const float*)d_in[0];
    const int*   ei  = (const int*)d_in[1];
    const float* W1  = (const float*)d_in[2];
    const float* b1  = (const float*)d_in[3];
    const float* Wc0 = (const float*)d_in[4];
    const float* bc0 = (const float*)d_in[5];
    const float* Wc1 = (const float*)d_in[6];
    const float* bc1 = (const float*)d_in[7];
    const float* W2  = (const float*)d_in[8];
    const float* b2  = (const float*)d_in[9];
    float* out = (float*)d_out;

    long long E = (long long)in_sizes[1] / 2;
    int nt = (int)((E + TILE_B - 1) / TILE_B);

    char* p = (char*)d_ws;
    float* dinv    = (float*)p;          p = align256(p + sizeof(float) * N_NODES);
    int* row_start = (int*)p;            p = align256(p + sizeof(int) * (N_NODES + 1));
    int* bcnt      = (int*)p;            p = align256(p + sizeof(int) * NBKT);
    int* bkt_base  = (int*)p;            p = align256(p + sizeof(int) * (NBKT + 1));
    int* thist     = (int*)p;            p = align256(p + sizeof(int) * (size_t)nt * NBKT);
    int* tbase     = (int*)p;            p = align256(p + sizeof(int) * (size_t)nt * NBKT);
    int* pairs     = (int*)p;            p = align256(p + sizeof(int) * E);
    float* h       = (float*)p;          p = align256(p + sizeof(float) * (size_t)N_NODES * HIDDEN);
    __half* tmpp   = (__half*)p;         p = align256(p + sizeof(__half) * (size_t)N_NODES * HIDDEN);

    const int nblk_node = (N_NODES + 255) / 256;
    const int nblk_bcnt = (int)((E + 2 * TILE_B - 1) / (2 * TILE_B));
    const int nblk_aggr = (int)(((long long)N_NODES * 64 + 255) / 256);

    k_zero<<<1, 1024, 0, stream>>>(bcnt);

    k_bcnt<<<nblk_bcnt, 512, 0, stream>>>(ei, E, nt, bcnt, thist);
    k_tscan<<<NBKT, 256, 0, stream>>>(thist, bcnt, nt, tbase, bkt_base);
    k_bucket<<<nt, 512, 0, stream>>>(ei, E, thist, tbase, pairs);
    k_csr<<<NBKT, 256, 0, stream>>>(bkt_base, pairs, row_start, dinv, (int)E);

    // conv 1 (lin1 fused into the dense transform)
    k_lin1f<<<nblk_node, 512, 0, stream>>>(x, W1, b1, Wc0, dinv, tmpp);
    k_aggr<<<nblk_aggr, 256, 0, stream>>>(row_start, pairs, tmpp, dinv, bc0, h);

    // conv 2
    k_mm16<<<nblk_node, 256, 0, stream>>>(h, Wc1, dinv, tmpp);
    k_aggr<<<nblk_aggr, 256, 0, stream>>>(row_start, pairs, tmpp, dinv, bc1, h);

    k_out<<<nblk_node, 256, 0, stream>>>(h, W2, b2, out);
}

// Round 17
// 181.126 us; speedup vs baseline: 1.5926x; 1.0439x over previous
//
#include <hip/hip_runtime.h>
#include <hip/hip_fp16.h>
#include <math.h>

#define N_NODES 100000
#define F_IN    100
#define HIDDEN  16
#define N_CLASS 18

#define BKT_SHIFT 7
#define BKT_NODES 128                                   // nodes per bucket
#define NBKT ((N_NODES + BKT_NODES - 1) / BKT_NODES)    // 782
#define TILE_B 4096                                     // edges per split tile
#define SORT_CAP 5120                                   // max edges per bucket

// ---- inline edge dtype detection: int64 little-endian (values < 2^31) has all-zero odd words
__device__ __forceinline__ int detect64(const int* __restrict__ ei) {
    int z = 1;
#pragma unroll
    for (int i = 0; i < 16; ++i)
        if (ei[2 * i + 1] != 0) z = 0;
    return z;
}

__device__ __forceinline__ int edge_at(const int* __restrict__ ei, long long idx, int is64) {
    return is64 ? ei[2 * idx] : ei[idx];
}

// ---- zero the 782-int bucket-count array
__global__ __launch_bounds__(1024) void k_zero(int* __restrict__ bcnt) {
    int i = threadIdx.x;
    if (i < NBKT) bcnt[i] = 0;
}

// ---- per-tile bucket histograms (2 tiles of 4096 per block) + global bucket counts
__global__ __launch_bounds__(512) void k_bcnt(const int* __restrict__ ei, long long E,
                                              int nt,
                                              int* __restrict__ bcnt,
                                              int* __restrict__ thist) {
    __shared__ int hist0[NBKT];
    __shared__ int hist1[NBKT];
    int tid = threadIdx.x;
    for (int i = tid; i < NBKT; i += 512) { hist0[i] = 0; hist1[i] = 0; }
    __syncthreads();
    int is64 = detect64(ei);
    long long base = (long long)blockIdx.x * (2 * TILE_B);
    long long rem = E - base;
    int ntot = (int)((rem < (long long)(2 * TILE_B)) ? rem : (long long)(2 * TILE_B));
    int n0 = ntot < TILE_B ? ntot : TILE_B;
    int n1 = ntot - n0;
    for (int i = tid; i < n0; i += 512) {
        int d = edge_at(ei, E + base + i, is64);
        atomicAdd(&hist0[d >> BKT_SHIFT], 1);
    }
    for (int i = tid; i < n1; i += 512) {
        int d = edge_at(ei, E + base + TILE_B + i, is64);
        atomicAdd(&hist1[d >> BKT_SHIFT], 1);
    }
    __syncthreads();
    int t0 = blockIdx.x * 2, t1 = t0 + 1;
    for (int b = tid; b < NBKT; b += 512) {
        int c0 = hist0[b], c1 = hist1[b];
        thist[t0 * NBKT + b] = c0;
        if (n1 > 0) thist[t1 * NBKT + b] = c1;
        int c = c0 + c1;
        if (c) atomicAdd(&bcnt[b], c);
    }
}

// ---- per-bucket prefix over tiles (block b), with bkt_base reduction fused in
__global__ __launch_bounds__(256) void k_tscan(const int* __restrict__ thist,
                                               const int* __restrict__ bcnt,
                                               int nt,
                                               int* __restrict__ tbase,
                                               int* __restrict__ bkt_base) {
    __shared__ int ts[256];
    __shared__ int red[256];
    int b = blockIdx.x, tid = threadIdx.x;
    int partial = 0;
    for (int i = tid; i < b; i += 256) partial += bcnt[i];
    red[tid] = partial;
    __syncthreads();
    for (int off = 128; off > 0; off >>= 1) {
        if (tid < off) red[tid] += red[tid + off];
        __syncthreads();
    }
    int base = red[0];
    if (tid == 0) bkt_base[b] = base;
    int t0 = tid * 4;
    int c[4];
#pragma unroll
    for (int j = 0; j < 4; ++j) {
        int t = t0 + j;
        c[j] = (t < nt) ? thist[t * NBKT + b] : 0;
    }
    int s = c[0] + c[1] + c[2] + c[3];
    ts[tid] = s;
    __syncthreads();
    for (int off = 1; off < 256; off <<= 1) {
        int t = (tid >= off) ? ts[tid - off] : 0;
        __syncthreads();
        ts[tid] += t;
        __syncthreads();
    }
    int run = base + ts[tid] - s;
#pragma unroll
    for (int j = 0; j < 4; ++j) {
        int t = t0 + j;
        if (t < nt) { tbase[t * NBKT + b] = run; run += c[j]; }
    }
}

// ---- split: per-tile counting sort by bucket; SINGLE edge-read pass (LDS-staged values)
__global__ __launch_bounds__(512) void k_bucket(const int* __restrict__ ei, long long E,
                                                const int* __restrict__ thist,
                                                const int* __restrict__ tbase,
                                                int* __restrict__ pairs) {
    __shared__ int lbase[NBKT];
    __shared__ int gbase[NBKT];
    __shared__ int lcur[NBKT];
    __shared__ int lpair[TILE_B];                 // packed value, bucket-grouped
    __shared__ unsigned short lbkt[TILE_B];       // bucket id per slot
    __shared__ int ts[512];
    int tid = threadIdx.x;
    int t = blockIdx.x;
    int is64 = detect64(ei);
    long long e0 = (long long)t * TILE_B;
    int n = (int)(((E - e0) < (long long)TILE_B) ? (E - e0) : (long long)TILE_B);

    int b0 = tid * 2;
    int h0 = (b0 + 0 < NBKT) ? thist[t * NBKT + b0 + 0] : 0;
    int h1 = (b0 + 1 < NBKT) ? thist[t * NBKT + b0 + 1] : 0;
    int tsum = h0 + h1;
    ts[tid] = tsum;
    for (int b = tid; b < NBKT; b += 512) gbase[b] = tbase[t * NBKT + b];
    __syncthreads();
    for (int off = 1; off < 512; off <<= 1) {
        int tv = (tid >= off) ? ts[tid - off] : 0;
        __syncthreads();
        ts[tid] += tv;
        __syncthreads();
    }
    int eb = ts[tid] - tsum;
    if (b0 + 0 < NBKT) { lbase[b0 + 0] = eb;      lcur[b0 + 0] = eb; }
    if (b0 + 1 < NBKT) { lbase[b0 + 1] = eb + h0; lcur[b0 + 1] = eb + h0; }
    __syncthreads();

    // single pass: read src+dst once, bin packed value + bucket id into LDS
    for (int i = tid; i < n; i += 512) {
        int s = edge_at(ei, e0 + i, is64);
        int d = edge_at(ei, E + e0 + i, is64);
        int b = d >> BKT_SHIFT;
        int l = atomicAdd(&lcur[b], 1);
        lpair[l] = s | ((d & (BKT_NODES - 1)) << 17);
        lbkt[l] = (unsigned short)b;
    }
    __syncthreads();

    // write out from LDS: consecutive k within a bucket-run -> consecutive positions
    for (int k = tid; k < n; k += 512) {
        int b = lbkt[k];
        int pos = gbase[b] + (k - lbase[b]);
        pairs[pos] = lpair[k];
    }
}

// ---- fused CSR finalize: per bucket -> per-node counts, dinv, row_start, in-place sort
__global__ __launch_bounds__(256) void k_csr(const int* __restrict__ bkt_base,
                                             int* __restrict__ pairs,
                                             int* __restrict__ row_start,
                                             float* __restrict__ dinv,
                                             int Ei) {
    __shared__ int stage[SORT_CAP];
    __shared__ int lc[BKT_NODES];
    __shared__ int rs[BKT_NODES];
    int bk = blockIdx.x, tid = threadIdx.x;
    int i0 = bkt_base[bk];
    int i1 = (bk == NBKT - 1) ? Ei : bkt_base[bk + 1];
    int m = i1 - i0;
    if (tid < BKT_NODES) lc[tid] = 0;
    __syncthreads();
    for (int i = tid; i < m; i += 256) {
        int v = pairs[i0 + i];
        stage[i] = v;
        atomicAdd(&lc[v >> 17], 1);
    }
    __syncthreads();
    if (tid < BKT_NODES) rs[tid] = lc[tid];
    __syncthreads();
    for (int off = 1; off < BKT_NODES; off <<= 1) {
        int t = (tid >= off && tid < BKT_NODES) ? rs[tid - off] : 0;
        __syncthreads();
        if (tid < BKT_NODES) rs[tid] += t;
        __syncthreads();
    }
    int node = bk * BKT_NODES + tid;
    int ex = 0;
    if (tid < BKT_NODES) {
        int c = lc[tid];
        ex = rs[tid] - c;
        if (node < N_NODES) {
            row_start[node] = i0 + ex;
            dinv[node] = rsqrtf((float)c + 1.0f);
        }
    }
    if (bk == NBKT - 1 && tid == 0) row_start[N_NODES] = i1;
    __syncthreads();
    if (tid < BKT_NODES) lc[tid] = ex;
    __syncthreads();
    for (int i = tid; i < m; i += 256) {
        int v = stage[i];
        int pos = atomicAdd(&lc[v >> 17], 1);
        pairs[i0 + pos] = v & 0x1FFFF;
    }
}

// ---- fused split-K: tmpp = fp16( dinv * ( relu(x@W1+b1) @ Wc0 ) ); 2 threads/node
__global__ __launch_bounds__(512) void k_lin1f(const float* __restrict__ x,
                                               const float* __restrict__ W1,
                                               const float* __restrict__ b1,
                                               const float* __restrict__ Wc0,
                                               const float* __restrict__ dinv,
                                               __half* __restrict__ tmpp) {
    __shared__ float sW[F_IN * HIDDEN];
    __shared__ float sb[HIDDEN];
    __shared__ float sW2[HIDDEN * HIDDEN];
    for (int i = threadIdx.x; i < F_IN * HIDDEN; i += 512) sW[i] = W1[i];
    if (threadIdx.x < HIDDEN) sb[threadIdx.x] = b1[threadIdx.x];
    if (threadIdx.x >= 32 && threadIdx.x < 32 + HIDDEN * HIDDEN)
        sW2[threadIdx.x - 32] = Wc0[threadIdx.x - 32];
    __syncthreads();
    int node = blockIdx.x * 256 + (threadIdx.x >> 1);
    int half = threadIdx.x & 1;
    if (node >= N_NODES) return;

    float acc[HIDDEN];
#pragma unroll
    for (int j = 0; j < HIDDEN; ++j) acc[j] = half ? 0.0f : sb[j];

    const float4* x4 = reinterpret_cast<const float4*>(x + (long long)node * F_IN);
    int k40 = half ? 13 : 0;
    int k41 = half ? 25 : 13;
    for (int k4 = k40; k4 < k41; ++k4) {
        float4 xv = x4[k4];
        const float* w = &sW[k4 * 4 * HIDDEN];
#pragma unroll
        for (int j = 0; j < HIDDEN; ++j) {
            acc[j] += xv.x * w[0 * HIDDEN + j];
            acc[j] += xv.y * w[1 * HIDDEN + j];
            acc[j] += xv.z * w[2 * HIDDEN + j];
            acc[j] += xv.w * w[3 * HIDDEN + j];
        }
    }
#pragma unroll
    for (int j = 0; j < HIDDEN; ++j) {
        acc[j] += __shfl_xor(acc[j], 1);
        acc[j] = fmaxf(acc[j], 0.0f);
    }
    float out[8];
#pragma unroll
    for (int j = 0; j < 8; ++j) out[j] = 0.0f;
    int j0 = half * 8;
#pragma unroll
    for (int k = 0; k < HIDDEN; ++k) {
        float hk = acc[k];
#pragma unroll
        for (int j = 0; j < 8; ++j) out[j] += hk * sW2[k * HIDDEN + j0 + j];
    }
    float di = dinv[node];
    __half2 packed[4];
#pragma unroll
    for (int j = 0; j < 4; ++j)
        packed[j] = __floats2half2_rn(di * out[2 * j], di * out[2 * j + 1]);
    *reinterpret_cast<float4*>(tmpp + (long long)node * HIDDEN + half * 8) =
        *reinterpret_cast<const float4*>(packed);
}

// ---- tmp' = fp16( dinv[i] * (h @ W) );  h is fp16 now
__global__ __launch_bounds__(256) void k_mm16(const __half* __restrict__ h,
                                              const float* __restrict__ W,
                                              const float* __restrict__ dinv,
                                              __half* __restrict__ tmpp) {
    __shared__ float sW[HIDDEN * HIDDEN];
    if (threadIdx.x < HIDDEN * HIDDEN) sW[threadIdx.x] = W[threadIdx.x];
    __syncthreads();
    int node = blockIdx.x * 256 + threadIdx.x;
    if (node >= N_NODES) return;

    float hv[HIDDEN];
    const float4* hr = reinterpret_cast<const float4*>(h + (long long)node * HIDDEN);
#pragma unroll
    for (int q = 0; q < 2; ++q) {
        float4 v = hr[q];
        const __half2* h2 = reinterpret_cast<const __half2*>(&v);
#pragma unroll
        for (int j = 0; j < 4; ++j) {
            float2 f = __half22float2(h2[j]);
            hv[q * 8 + 2 * j + 0] = f.x;
            hv[q * 8 + 2 * j + 1] = f.y;
        }
    }
    float di = dinv[node];
    float out[HIDDEN];
#pragma unroll
    for (int j = 0; j < HIDDEN; ++j) out[j] = 0.0f;
#pragma unroll
    for (int k = 0; k < HIDDEN; ++k) {
        float hk = hv[k];
#pragma unroll
        for (int j = 0; j < HIDDEN; ++j) out[j] += hk * sW[k * HIDDEN + j];
    }
    __half2 packed[8];
#pragma unroll
    for (int j = 0; j < 8; ++j)
        packed[j] = __floats2half2_rn(di * out[2 * j], di * out[2 * j + 1]);
    float4* tp = reinterpret_cast<float4*>(tmpp + (long long)node * HIDDEN);
    const float4* ps = reinterpret_cast<const float4*>(packed);
    tp[0] = ps[0];
    tp[1] = ps[1];
}

// ---- wave-per-node register pull, 4 lanes/row; 2-deep hoisted loads; fused epilogue
// h[n] = fp16( relu(dinv[n]*(sum_src tmpp[src] + tmpp[n]) + b) )
__global__ __launch_bounds__(256) void k_aggr(const int* __restrict__ row_start,
                                              const int* __restrict__ srcs,
                                              const __half* __restrict__ tmpp,
                                              const float* __restrict__ dinv,
                                              const float* __restrict__ b,
                                              __half* __restrict__ h) {
    int wave = (blockIdx.x * 256 + threadIdx.x) >> 6;   // node id
    if (wave >= N_NODES) return;
    int lane = threadIdx.x & 63;
    int es = lane >> 2;        // edge slot 0..15
    int fq = lane & 3;         // feature quarter (4 halves = 8 B)

    int s0 = row_start[wave], s1 = row_start[wave + 1];
    float a0 = 0.0f, a1 = 0.0f, a2 = 0.0f, a3 = 0.0f;
    const float2* t2 = reinterpret_cast<const float2*>(tmpp);

    for (int e = s0 + es; e < s1; e += 32) {
        int eb  = e + 16;
        int ebc = (eb < s1) ? eb : (s1 - 1);
        float mb = (eb < s1) ? 1.0f : 0.0f;
        int sa = srcs[e];
        int sb = srcs[ebc];
        float2 ra = t2[(long long)sa * 4 + fq];
        float2 rb = t2[(long long)sb * 4 + fq];
        const __half2* ha = reinterpret_cast<const __half2*>(&ra);
        const __half2* hb = reinterpret_cast<const __half2*>(&rb);
        float2 fa0 = __half22float2(ha[0]);
        float2 fa1 = __half22float2(ha[1]);
        float2 fb0 = __half22float2(hb[0]);
        float2 fb1 = __half22float2(hb[1]);
        a0 += fa0.x + mb * fb0.x;
        a1 += fa0.y + mb * fb0.y;
        a2 += fa1.x + mb * fb1.x;
        a3 += fa1.y + mb * fb1.y;
    }
#pragma unroll
    for (int m = 4; m <= 32; m <<= 1) {
        a0 += __shfl_xor(a0, m);
        a1 += __shfl_xor(a1, m);
        a2 += __shfl_xor(a2, m);
        a3 += __shfl_xor(a3, m);
    }
    if (es == 0) {
        float2 sv = t2[(long long)wave * 4 + fq];
        const __half2* s2 = reinterpret_cast<const __half2*>(&sv);
        float2 f0 = __half22float2(s2[0]);
        float2 f1 = __half22float2(s2[1]);
        float di = dinv[wave];
        float4 bv = *(reinterpret_cast<const float4*>(b) + fq);
        __half2 pk[2];
        pk[0] = __floats2half2_rn(fmaxf(di * (a0 + f0.x) + bv.x, 0.0f),
                                  fmaxf(di * (a1 + f0.y) + bv.y, 0.0f));
        pk[1] = __floats2half2_rn(fmaxf(di * (a2 + f1.x) + bv.z, 0.0f),
                                  fmaxf(di * (a3 + f1.y) + bv.w, 0.0f));
        *reinterpret_cast<float2*>(h + (long long)wave * HIDDEN + fq * 4) =
            *reinterpret_cast<const float2*>(pk);
    }
}

// ---- out = log_softmax(h @ W2 + b2);  h is fp16 now
__global__ __launch_bounds__(256) void k_out(const __half* __restrict__ h,
                                             const float* __restrict__ W2,
                                             const float* __restrict__ b2,
                                             float* __restrict__ out) {
    __shared__ float sW[HIDDEN * N_CLASS];
    __shared__ float sb[N_CLASS];
    for (int i = threadIdx.x; i < HIDDEN * N_CLASS; i += 256) sW[i] = W2[i];
    if (threadIdx.x < N_CLASS) sb[threadIdx.x] = b2[threadIdx.x];
    __syncthreads();
    int node = blockIdx.x * 256 + threadIdx.x;
    if (node >= N_NODES) return;

    float hv[HIDDEN];
    const float4* hr = reinterpret_cast<const float4*>(h + (long long)node * HIDDEN);
#pragma unroll
    for (int q = 0; q < 2; ++q) {
        float4 v = hr[q];
        const __half2* h2 = reinterpret_cast<const __half2*>(&v);
#pragma unroll
        for (int j = 0; j < 4; ++j) {
            float2 f = __half22float2(h2[j]);
            hv[q * 8 + 2 * j + 0] = f.x;
            hv[q * 8 + 2 * j + 1] = f.y;
        }
    }
    float z[N_CLASS];
#pragma unroll
    for (int c = 0; c < N_CLASS; ++c) z[c] = sb[c];
#pragma unroll
    for (int k = 0; k < HIDDEN; ++k) {
        float hk = hv[k];
#pragma unroll
        for (int c = 0; c < N_CLASS; ++c) z[c] += hk * sW[k * N_CLASS + c];
    }
    float m = z[0];
#pragma unroll
    for (int c = 1; c < N_CLASS; ++c) m = fmaxf(m, z[c]);
    float ssum = 0.0f;
#pragma unroll
    for (int c = 0; c < N_CLASS; ++c) ssum += expf(z[c] - m);
    float l = m + logf(ssum);
    float* orow = out + (long long)node * N_CLASS;
#pragma unroll
    for (int c = 0; c < N_CLASS; ++c) orow[c] = z[c] - l;
}

static inline char* align256(char* p) {
    return (char*)(((size_t)p + 255) & ~(size_t)255);
}

extern "C" void kernel_launch(void* const* d_in, const int* in_sizes, int n_in,
                              void* d_out, int out_size, void* d_ws, size_t ws_size,
                              hipStream_t stream) {
    const float* x   = (const float*)d_in[0];
    const int*   ei  = (const int*)d_in[1];
    const float* W1  = (const float*)d_in[2];
    const float* b1  = (const float*)d_in[3];
    const float* Wc0 = (const float*)d_in[4];
    const float* bc0 = (const float*)d_in[5];
    const float* Wc1 = (const float*)d_in[6];
    const float* bc1 = (const float*)d_in[7];
    const float* W2  = (const float*)d_in[8];
    const float* b2  = (const float*)d_in[9];
    float* out = (float*)d_out;

    long long E = (long long)in_sizes[1] / 2;
    int nt = (int)((E + TILE_B - 1) / TILE_B);

    char* p = (char*)d_ws;
    float* dinv    = (float*)p;          p = align256(p + sizeof(float) * N_NODES);
    int* row_start = (int*)p;            p = align256(p + sizeof(int) * (N_NODES + 1));
    int* bcnt      = (int*)p;            p = align256(p + sizeof(int) * NBKT);
    int* bkt_base  = (int*)p;            p = align256(p + sizeof(int) * (NBKT + 1));
    int* thist     = (int*)p;            p = align256(p + sizeof(int) * (size_t)nt * NBKT);
    int* tbase     = (int*)p;            p = align256(p + sizeof(int) * (size_t)nt * NBKT);
    int* pairs     = (int*)p;            p = align256(p + sizeof(int) * E);
    __half* h      = (__half*)p;         p = align256(p + sizeof(__half) * (size_t)N_NODES * HIDDEN);
    __half* tmpp   = (__half*)p;         p = align256(p + sizeof(__half) * (size_t)N_NODES * HIDDEN);

    const int nblk_node = (N_NODES + 255) / 256;
    const int nblk_bcnt = (int)((E + 2 * TILE_B - 1) / (2 * TILE_B));
    const int nblk_aggr = (int)(((long long)N_NODES * 64 + 255) / 256);

    k_zero<<<1, 1024, 0, stream>>>(bcnt);

    k_bcnt<<<nblk_bcnt, 512, 0, stream>>>(ei, E, nt, bcnt, thist);
    k_tscan<<<NBKT, 256, 0, stream>>>(thist, bcnt, nt, tbase, bkt_base);
    k_bucket<<<nt, 512, 0, stream>>>(ei, E, thist, tbase, pairs);
    k_csr<<<NBKT, 256, 0, stream>>>(bkt_base, pairs, row_start, dinv, (int)E);

    // conv 1 (lin1 fused into the dense transform)
    k_lin1f<<<nblk_node, 512, 0, stream>>>(x, W1, b1, Wc0, dinv, tmpp);
    k_aggr<<<nblk_aggr, 256, 0, stream>>>(row_start, pairs, tmpp, dinv, bc0, h);

    // conv 2
    k_mm16<<<nblk_node, 256, 0, stream>>>(h, Wc1, dinv, tmpp);
    k_aggr<<<nblk_aggr, 256, 0, stream>>>(row_start, pairs, tmpp, dinv, bc1, h);

    k_out<<<nblk_node, 256, 0, stream>>>(h, W2, b2, out);
}